// Round 4
// baseline (65.171 us; speedup 1.0000x reference)
//
#include <hip/hip_runtime.h>

typedef short s8v __attribute__((ext_vector_type(8)));
typedef float f4v __attribute__((ext_vector_type(4)));
typedef float f16v __attribute__((ext_vector_type(16)));

#define ND 4096
#define NMASK 4095

__device__ __forceinline__ unsigned short f2bf(float f) {
  __bf16 h = (__bf16)f;
  return __builtin_bit_cast(unsigned short, h);
}

// Prep: build the 8-fold sliding-window W table in GLOBAL memory (d_ws):
// wlg[8s+t] = bf16(W[(s+t)&4095]), 32768 bf16 = 64 KB. Any 8-elem circulant
// window starting at s is ONE aligned 16B load at byte 16s.
__global__ __launch_bounds__(256)
void wl_build(const float* __restrict__ W, unsigned int* __restrict__ wlg) {
  const int m = blockIdx.x * 256 + threadIdx.x;   // uint slot 0..16383
  const int e0 = m << 1, e1 = e0 + 1;
  const int i0 = ((e0 >> 3) + (e0 & 7)) & NMASK;
  const int i1 = ((e1 >> 3) + (e1 & 7)) & NMASK;
  wlg[m] = (unsigned int)f2bf(W[i0]) | ((unsigned int)f2bf(W[i1]) << 16);
}

// BM=64, BN=128. 512 threads = 8 waves: wn = wv&1 (64-col band), kb = wv>>1
// owning a CONTIGUOUS K-quarter [kb*1024, kb*1024+1024). Wave tile 64x64
// (2x2 frags of 32x32x16), positional cross-wave LDS reduction at the end.
// B fragments come straight from global wlg (L1-hot ~8KB window) — LDS holds
// only A. A layout (k-major, conflict-free, no swizzle):
//   elem(kb,buf,step,lh,row,j) = ((((kb*2+buf)*2+step)*2+lh)*64+row)*8 + j
// Frag reads and staging writes are contiguous 512B half-wave blocks.
// Each kb's region is staged by exactly its own wn-pair (threads t>>7==kb).
// 32 barrier intervals of 32 k each (vs 64 before).
__global__ __launch_bounds__(512, 4)
void circ_mm(const float* __restrict__ X, const unsigned short* __restrict__ wlg,
             const float* __restrict__ bias, float* __restrict__ C) {
  extern __shared__ unsigned short smem[];
  unsigned short* __restrict__ al = smem;          // 16384 elems = 32 KB (A only)

  const int tid = threadIdx.x;
  const int bid = blockIdx.x;
  // XCD-aware mapping: XCD x serves m-panels {x, x+8}; 32 n-tiles share the
  // 2 MB X panel in that XCD's L2.
  const int x = bid & 7;
  const int i = bid >> 3;
  const int m0 = (x + ((i >> 5) << 3)) << 6;   // 0..960
  const int n0 = (i & 31) << 7;                // 0..3968

  // ---- A staging geometry: thread t stages for kb-region kbp = t>>7 ----
  const int kbp   = tid >> 7;        // 0..3 (== its own wave's kb)
  const int thr2  = tid & 127;
  const int srow  = thr2 >> 1;       // 0..63
  const int khalf = tid & 1;         // which 16-k half (== step)
  const float* gA = X + (m0 + srow) * ND + kbp * 1024 + khalf * 16;
  const int wbase = kbp * 4096 + khalf * 1024 + srow * 8;  // lh=0; lh=1 -> +512

  // ---- fragment geometry (mfma_f32_32x32x16_bf16) ----
  const int lane = tid & 63;
  const int lc = lane & 31;
  const int lh  = lane >> 5;
  const int lh8 = lh << 3;
  const int wv = tid >> 6;          // 0..7
  const int wn = wv & 1;            // 64-col band within block
  const int kb = wv >> 1;           // contiguous K-quarter
  const int kbase = kb << 10;

  int aoff[2][2];                   // [step][mf], buf=0
  #pragma unroll
  for (int st = 0; st < 2; ++st)
    #pragma unroll
    for (int mf = 0; mf < 2; ++mf)
      aoff[st][mf] = kb * 4096 + st * 1024 + lh * 512 + (mf * 32 + lc) * 8;

  int c0f[2];                       // (lh8 - col) & 4095 per n-fragment
  #pragma unroll
  for (int nf = 0; nf < 2; ++nf) {
    const int col = n0 + wn * 64 + nf * 32 + lc;
    c0f[nf] = (lh8 - col) & NMASK;
  }

  f16v acc[2][2];
  #pragma unroll
  for (int mf = 0; mf < 2; ++mf)
    #pragma unroll
    for (int nf = 0; nf < 2; ++nf)
      #pragma unroll
      for (int e = 0; e < 16; ++e) acc[mf][nf][e] = 0.f;

  // ---- prologue: stage interval 0 into buf 0 ----
  {
    f4v g0 = *(const f4v*)(gA + 0);
    f4v g1 = *(const f4v*)(gA + 4);
    f4v g2 = *(const f4v*)(gA + 8);
    f4v g3 = *(const f4v*)(gA + 12);
    s8v u0, u1;
    #pragma unroll
    for (int j = 0; j < 4; ++j) {
      u0[j] = (short)f2bf(g0[j]); u0[4 + j] = (short)f2bf(g1[j]);
      u1[j] = (short)f2bf(g2[j]); u1[4 + j] = (short)f2bf(g3[j]);
    }
    *(s8v*)(&al[wbase])       = u0;   // lh=0 octet
    *(s8v*)(&al[wbase + 512]) = u1;   // lh=1 octet
  }
  __syncthreads();

  // ---- main loop: 32 intervals of 32 k; T14 split; dbuf via +2048 elems ----
  for (int it = 0; it < 32; ++it) {
    const int bo = (it & 1) << 11;   // buf elem offset

    f4v g0, g1, g2, g3;
    if (it < 31) {                   // issue next-interval global loads first
      const float* gp = gA + (it + 1) * 32;
      g0 = *(const f4v*)(gp + 0);
      g1 = *(const f4v*)(gp + 4);
      g2 = *(const f4v*)(gp + 8);
      g3 = *(const f4v*)(gp + 12);
    }

    #pragma unroll
    for (int st = 0; st < 2; ++st) {
      const s8v a0 = *(const s8v*)(&al[bo + aoff[st][0]]);
      const s8v a1 = *(const s8v*)(&al[bo + aoff[st][1]]);
      const int kg = kbase + it * 32 + st * 16;
      const int s0 = (kg + c0f[0]) & NMASK;
      const int s1 = (kg + c0f[1]) & NMASK;
      const s8v b0 = *(const s8v*)(wlg + (s0 << 3));
      const s8v b1 = *(const s8v*)(wlg + (s1 << 3));
      acc[0][0] = __builtin_amdgcn_mfma_f32_32x32x16_bf16(a0, b0, acc[0][0], 0, 0, 0);
      acc[1][0] = __builtin_amdgcn_mfma_f32_32x32x16_bf16(a1, b0, acc[1][0], 0, 0, 0);
      acc[0][1] = __builtin_amdgcn_mfma_f32_32x32x16_bf16(a0, b1, acc[0][1], 0, 0, 0);
      acc[1][1] = __builtin_amdgcn_mfma_f32_32x32x16_bf16(a1, b1, acc[1][1], 0, 0, 0);
    }

    if (it < 31) {                   // convert + LDS-write after compute
      unsigned short* aw = al + (bo ^ 2048);
      s8v u0, u1;
      #pragma unroll
      for (int j = 0; j < 4; ++j) {
        u0[j] = (short)f2bf(g0[j]); u0[4 + j] = (short)f2bf(g1[j]);
        u1[j] = (short)f2bf(g2[j]); u1[4 + j] = (short)f2bf(g3[j]);
      }
      *(s8v*)(&aw[wbase])       = u0;
      *(s8v*)(&aw[wbase + 512]) = u1;
    }
    __syncthreads();
  }

  // ---- epilogue: positional 4-way K reduction (b128), then bias + store ----
  // Lane l of (wn,kb) holds the same (row,col) set as lane l of (wn,kb');
  // exchange the 64 acc floats positionally.
  float* red = (float*)smem;        // 4 bands x 16 KB = 64 KB (overlays al)
  float* rb;

  if (kb >= 2) {
    rb = red + ((kb - 2) * 2 + wn) * 4096;
    #pragma unroll
    for (int mf = 0; mf < 2; ++mf)
      #pragma unroll
      for (int nf = 0; nf < 2; ++nf)
        #pragma unroll
        for (int q = 0; q < 4; ++q) {
          const int j = ((mf * 2 + nf) * 4 + q);
          f4v v;
          #pragma unroll
          for (int e = 0; e < 4; ++e) v[e] = acc[mf][nf][q * 4 + e];
          *(f4v*)(&rb[(j * 64 + lane) * 4]) = v;
        }
  }
  __syncthreads();
  if (kb < 2) {
    rb = red + (kb * 2 + wn) * 4096;
    #pragma unroll
    for (int mf = 0; mf < 2; ++mf)
      #pragma unroll
      for (int nf = 0; nf < 2; ++nf)
        #pragma unroll
        for (int q = 0; q < 4; ++q) {
          const int j = ((mf * 2 + nf) * 4 + q);
          const f4v v = *(const f4v*)(&rb[(j * 64 + lane) * 4]);
          #pragma unroll
          for (int e = 0; e < 4; ++e) acc[mf][nf][q * 4 + e] += v[e];
        }
  }
  __syncthreads();
  if (kb == 1) {
    rb = red + wn * 4096;
    #pragma unroll
    for (int mf = 0; mf < 2; ++mf)
      #pragma unroll
      for (int nf = 0; nf < 2; ++nf)
        #pragma unroll
        for (int q = 0; q < 4; ++q) {
          const int j = ((mf * 2 + nf) * 4 + q);
          f4v v;
          #pragma unroll
          for (int e = 0; e < 4; ++e) v[e] = acc[mf][nf][q * 4 + e];
          *(f4v*)(&rb[(j * 64 + lane) * 4]) = v;
        }
  }
  __syncthreads();
  if (kb == 0) {
    rb = red + wn * 4096;
    #pragma unroll
    for (int mf = 0; mf < 2; ++mf)
      #pragma unroll
      for (int nf = 0; nf < 2; ++nf)
        #pragma unroll
        for (int q = 0; q < 4; ++q) {
          const int j = ((mf * 2 + nf) * 4 + q);
          const f4v v = *(const f4v*)(&rb[(j * 64 + lane) * 4]);
          #pragma unroll
          for (int e = 0; e < 4; ++e) acc[mf][nf][q * 4 + e] += v[e];
        }
    const int lh4 = lh << 2;
    #pragma unroll
    for (int nf = 0; nf < 2; ++nf) {
      const int col = n0 + wn * 64 + nf * 32 + lc;
      const float bv = bias[col];
      #pragma unroll
      for (int mf = 0; mf < 2; ++mf)
        #pragma unroll
        for (int g = 0; g < 4; ++g) {
          const int row = m0 + mf * 32 + g * 8 + lh4;
          #pragma unroll
          for (int e = 0; e < 4; ++e)
            C[(row + e) * ND + col] = acc[mf][nf][g * 4 + e] + bv;
        }
    }
  }
}

extern "C" void kernel_launch(void* const* d_in, const int* in_sizes, int n_in,
                              void* d_out, int out_size, void* d_ws, size_t ws_size,
                              hipStream_t stream) {
  (void)hipFuncSetAttribute((const void*)circ_mm,
                            hipFuncAttributeMaxDynamicSharedMemorySize, 65536);
  const float* X    = (const float*)d_in[0];
  const float* W    = (const float*)d_in[1];
  const float* bias = (const float*)d_in[2];
  unsigned short* wlg = (unsigned short*)d_ws;   // 64 KB sliding-window table

  wl_build<<<dim3(64), dim3(256), 0, stream>>>(W, (unsigned int*)wlg);
  circ_mm<<<dim3(512), dim3(512), 65536, stream>>>(X, wlg, bias, (float*)d_out);
}

// Round 5
// 56.234 us; speedup vs baseline: 1.1589x; 1.1589x over previous
//
#include <hip/hip_runtime.h>

typedef short s8v __attribute__((ext_vector_type(8)));
typedef float f4v __attribute__((ext_vector_type(4)));
typedef float f16v __attribute__((ext_vector_type(16)));

#define ND 4096
#define NMASK 4095

__device__ __forceinline__ unsigned short f2bf(float f) {
  __bf16 h = (__bf16)f;
  return __builtin_bit_cast(unsigned short, h);
}

__device__ __forceinline__ void gload_lds16(const void* g, void* l) {
  __builtin_amdgcn_global_load_lds(
      (const __attribute__((address_space(1))) unsigned int*)g,
      (__attribute__((address_space(3))) unsigned int*)l, 16, 0, 0);
}

// Prep 1: 8-fold sliding-window W table in global (bf16, 64 KB):
// wlg[8s+t] = bf16(W[(s+t)&4095]) -> any 8-elem circulant window = one
// aligned 16B load at byte 16s.
__global__ __launch_bounds__(256)
void wl_build(const float* __restrict__ W, unsigned int* __restrict__ wlg) {
  const int m = blockIdx.x * 256 + threadIdx.x;   // uint slot 0..16383
  const int e0 = m << 1, e1 = e0 + 1;
  const int i0 = ((e0 >> 3) + (e0 & 7)) & NMASK;
  const int i1 = ((e1 >> 3) + (e1 & 7)) & NMASK;
  wlg[m] = (unsigned int)f2bf(W[i0]) | ((unsigned int)f2bf(W[i1]) << 16);
}

// Prep 2: X f32 -> bf16 (8 MB), enables global_load_lds direct A-staging.
__global__ __launch_bounds__(256)
void xcvt(const float* __restrict__ X, unsigned short* __restrict__ Y) {
  const int i = (blockIdx.x * 256 + threadIdx.x) << 3;
  const f4v a = *(const f4v*)(X + i);
  const f4v b = *(const f4v*)(X + i + 4);
  s8v u;
  #pragma unroll
  for (int j = 0; j < 4; ++j) {
    u[j] = (short)f2bf(a[j]); u[4 + j] = (short)f2bf(b[j]);
  }
  *(s8v*)(Y + i) = u;
}

// BM=64, BN=128, BK=64. 512 threads = 8 waves: wn = wv&1 (64-col band),
// kb = wv>>1 (k16-quarter of each 64-k tile). Wave tile 64x64 (2x2 frags of
// 32x32x16); positional cross-wave LDS reduction at the end.
// LDS: wl (64 KB, copied from wlg via global_load_lds) + A dbuf 2x8 KB.
// A tile [64 rows][64 k] bf16, 128B rows, staged by ONE global_load_lds_dwordx4
// per wave per tile (linear dest). Bank swizzle via pre-swizzled SOURCE:
// lane (row=wv*8+(lane>>3), seg=lane&7) fetches global segment seg^(row&7);
// fragment reads XOR the same involution -> conflict-free both sides (rule 21).
__global__ __launch_bounds__(512, 4)
void circ_mm(const unsigned short* __restrict__ Xb,
             const unsigned short* __restrict__ wlg,
             const float* __restrict__ bias, float* __restrict__ C) {
  extern __shared__ unsigned short smem[];
  unsigned char* __restrict__ sb = (unsigned char*)smem;   // byte view
  // bytes [0, 65536): wl ; [65536, 81920): A dbuf

  const int tid = threadIdx.x;
  const int bid = blockIdx.x;
  // XCD-aware mapping: XCD x serves m-panels {x, x+8}; 32 n-tiles share the
  // X panel in that XCD's L2.
  const int x = bid & 7;
  const int i = bid >> 3;
  const int m0 = (x + ((i >> 5) << 3)) << 6;   // 0..960
  const int n0 = (i & 31) << 7;                // 0..3968

  const int lane = tid & 63;
  const int wv = tid >> 6;          // 0..7
  const int wv1024 = wv << 10;

  // ---- async copy wl -> LDS (64 KB = 8 iters x 8 waves x 1 KB) ----
  #pragma unroll
  for (int it = 0; it < 8; ++it) {
    const int b = it * 8192 + wv1024;                  // wave-uniform base
    gload_lds16((const unsigned char*)wlg + b + lane * 16, sb + b);
  }

  // ---- A staging source (per-lane, seg pre-swizzled) ----
  const int srow = (lane >> 3);                 // row within wave's 8-row band
  const int sseg = (lane & 7) ^ (srow & 7);     // swizzled 16B segment
  const unsigned short* gAl = Xb + (m0 + wv * 8 + srow) * ND + sseg * 8;

  // ---- fragment geometry (mfma_f32_32x32x16_bf16) ----
  const int lc = lane & 31;
  const int lh = lane >> 5;
  const int lh8 = lh << 3;
  const int wn = wv & 1;            // 64-col band within block
  const int kb = wv >> 1;           // k16-quarter of each 64-k tile

  int aoffA[2];                     // byte offsets within A buf, per mf
  #pragma unroll
  for (int mf = 0; mf < 2; ++mf) {
    const int row = mf * 32 + lc;
    aoffA[mf] = 65536 + row * 128 + (((kb * 2 + lh) ^ (row & 7)) << 4);
  }

  int c0f[2];                       // (kb*16 + lh8 - col) & 4095
  #pragma unroll
  for (int nf = 0; nf < 2; ++nf) {
    const int col = n0 + wn * 64 + nf * 32 + lc;
    c0f[nf] = ((kb << 4) + lh8 - col) & NMASK;
  }

  f16v acc[2][2];
  #pragma unroll
  for (int mf = 0; mf < 2; ++mf)
    #pragma unroll
    for (int nf = 0; nf < 2; ++nf)
      #pragma unroll
      for (int e = 0; e < 16; ++e) acc[mf][nf][e] = 0.f;

  // ---- prologue: stage A tile 0 into buf 0 ----
  gload_lds16(gAl, sb + 65536 + wv1024);
  __syncthreads();

  // ---- main loop: 64 tiles of BK=64, one barrier per tile ----
  #pragma unroll 2
  for (int t = 0; t < 64; ++t) {
    const int bo = (t & 1) << 13;    // current buf byte offset

    if (t < 63)                      // async stage next tile (1 instr/wave)
      gload_lds16(gAl + (t + 1) * 64, sb + 65536 + (bo ^ 8192) + wv1024);

    const s8v a0 = *(const s8v*)(sb + bo + aoffA[0]);
    const s8v a1 = *(const s8v*)(sb + bo + aoffA[1]);
    const int kg = t << 6;
    const int s0 = (kg + c0f[0]) & NMASK;
    const int s1 = (kg + c0f[1]) & NMASK;
    const s8v b0 = *(const s8v*)(sb + (s0 << 4));
    const s8v b1 = *(const s8v*)(sb + (s1 << 4));

    acc[0][0] = __builtin_amdgcn_mfma_f32_32x32x16_bf16(a0, b0, acc[0][0], 0, 0, 0);
    acc[1][0] = __builtin_amdgcn_mfma_f32_32x32x16_bf16(a1, b0, acc[1][0], 0, 0, 0);
    acc[0][1] = __builtin_amdgcn_mfma_f32_32x32x16_bf16(a0, b1, acc[0][1], 0, 0, 0);
    acc[1][1] = __builtin_amdgcn_mfma_f32_32x32x16_bf16(a1, b1, acc[1][1], 0, 0, 0);

    __syncthreads();
  }

  // ---- epilogue: positional 4-way K reduction (b128), then bias + store ----
  float* red = (float*)smem;        // 4 bands x 16 KB = 64 KB (overlays wl)
  float* rb;

  if (kb >= 2) {
    rb = red + ((kb - 2) * 2 + wn) * 4096;
    #pragma unroll
    for (int mf = 0; mf < 2; ++mf)
      #pragma unroll
      for (int nf = 0; nf < 2; ++nf)
        #pragma unroll
        for (int q = 0; q < 4; ++q) {
          const int j = ((mf * 2 + nf) * 4 + q);
          f4v v;
          #pragma unroll
          for (int e = 0; e < 4; ++e) v[e] = acc[mf][nf][q * 4 + e];
          *(f4v*)(&rb[(j * 64 + lane) * 4]) = v;
        }
  }
  __syncthreads();
  if (kb < 2) {
    rb = red + (kb * 2 + wn) * 4096;
    #pragma unroll
    for (int mf = 0; mf < 2; ++mf)
      #pragma unroll
      for (int nf = 0; nf < 2; ++nf)
        #pragma unroll
        for (int q = 0; q < 4; ++q) {
          const int j = ((mf * 2 + nf) * 4 + q);
          const f4v v = *(const f4v*)(&rb[(j * 64 + lane) * 4]);
          #pragma unroll
          for (int e = 0; e < 4; ++e) acc[mf][nf][q * 4 + e] += v[e];
        }
  }
  __syncthreads();
  if (kb == 1) {
    rb = red + wn * 4096;
    #pragma unroll
    for (int mf = 0; mf < 2; ++mf)
      #pragma unroll
      for (int nf = 0; nf < 2; ++nf)
        #pragma unroll
        for (int q = 0; q < 4; ++q) {
          const int j = ((mf * 2 + nf) * 4 + q);
          f4v v;
          #pragma unroll
          for (int e = 0; e < 4; ++e) v[e] = acc[mf][nf][q * 4 + e];
          *(f4v*)(&rb[(j * 64 + lane) * 4]) = v;
        }
  }
  __syncthreads();
  if (kb == 0) {
    rb = red + wn * 4096;
    #pragma unroll
    for (int mf = 0; mf < 2; ++mf)
      #pragma unroll
      for (int nf = 0; nf < 2; ++nf)
        #pragma unroll
        for (int q = 0; q < 4; ++q) {
          const int j = ((mf * 2 + nf) * 4 + q);
          const f4v v = *(const f4v*)(&rb[(j * 64 + lane) * 4]);
          #pragma unroll
          for (int e = 0; e < 4; ++e) acc[mf][nf][q * 4 + e] += v[e];
        }
    const int lh4 = lh << 2;
    #pragma unroll
    for (int nf = 0; nf < 2; ++nf) {
      const int col = n0 + wn * 64 + nf * 32 + lc;
      const float bv = bias[col];
      #pragma unroll
      for (int mf = 0; mf < 2; ++mf)
        #pragma unroll
        for (int g = 0; g < 4; ++g) {
          const int row = m0 + mf * 32 + g * 8 + lh4;
          #pragma unroll
          for (int e = 0; e < 4; ++e)
            C[(row + e) * ND + col] = acc[mf][nf][g * 4 + e] + bv;
        }
    }
  }
}

extern "C" void kernel_launch(void* const* d_in, const int* in_sizes, int n_in,
                              void* d_out, int out_size, void* d_ws, size_t ws_size,
                              hipStream_t stream) {
  (void)hipFuncSetAttribute((const void*)circ_mm,
                            hipFuncAttributeMaxDynamicSharedMemorySize, 81920);
  const float* X    = (const float*)d_in[0];
  const float* W    = (const float*)d_in[1];
  const float* bias = (const float*)d_in[2];
  unsigned short* wlg = (unsigned short*)d_ws;            // 64 KB table
  unsigned short* Xb  = (unsigned short*)d_ws + 32768;    // 8 MB bf16 X

  wl_build<<<dim3(64), dim3(256), 0, stream>>>(W, (unsigned int*)wlg);
  xcvt<<<dim3(2048), dim3(256), 0, stream>>>(X, Xb);
  circ_mm<<<dim3(512), dim3(512), 81920, stream>>>(Xb, wlg, bias, (float*)d_out);
}

// Round 6
// 47.156 us; speedup vs baseline: 1.3820x; 1.1925x over previous
//
#include <hip/hip_runtime.h>

typedef short s8v __attribute__((ext_vector_type(8)));
typedef float f4v __attribute__((ext_vector_type(4)));
typedef float f16v __attribute__((ext_vector_type(16)));

#define ND 4096
#define NMASK 4095

__device__ __forceinline__ unsigned short f2bf(float f) {
  __bf16 h = (__bf16)f;
  return __builtin_bit_cast(unsigned short, h);
}

__device__ __forceinline__ void gload_lds16(const void* g, void* l) {
  __builtin_amdgcn_global_load_lds(
      (const __attribute__((address_space(1))) unsigned int*)g,
      (__attribute__((address_space(3))) unsigned int*)l, 16, 0, 0);
}

// Fused prep:
//  blocks [0,1024):  X f32 -> bf16 in OCTET-MAJOR layout
//                    Xpk[(oct*1024 + row)*8 + j] = bf16(X[row][oct*8+j])
//                    so an A-fragment read (32 lanes, same oct, consecutive
//                    rows) is 512B contiguous -> fully coalesced global load.
//  blocks [1024,1088): 8-fold sliding-window W table:
//                    wlg[8s+t] = bf16(W[(s+t)&4095]) -> any 8-elem circulant
//                    window = one aligned 16B load at byte 16s.
__global__ __launch_bounds__(256)
void prep(const float* __restrict__ X, const float* __restrict__ W,
          unsigned short* __restrict__ Xpk, unsigned int* __restrict__ wlg) {
  const int b = blockIdx.x;
  const int tid = threadIdx.x;
  if (b < 1024) {
    const int r0 = (b & 15) << 6;        // 64-row band
    const int k0 = (b >> 4) << 6;        // 64-k band
    const int r = tid >> 2;
    const int kseg = tid & 3;            // 16 k each
    const int row = r0 + r;
    const int k = k0 + (kseg << 4);
    const float* src = X + row * ND + k;
    const f4v g0 = *(const f4v*)(src + 0);
    const f4v g1 = *(const f4v*)(src + 4);
    const f4v g2 = *(const f4v*)(src + 8);
    const f4v g3 = *(const f4v*)(src + 12);
    s8v u0, u1;
    #pragma unroll
    for (int j = 0; j < 4; ++j) {
      u0[j] = (short)f2bf(g0[j]); u0[4 + j] = (short)f2bf(g1[j]);
      u1[j] = (short)f2bf(g2[j]); u1[4 + j] = (short)f2bf(g3[j]);
    }
    const int o0 = k >> 3;
    *(s8v*)(Xpk + ((o0 * 1024 + row) << 3))       = u0;
    *(s8v*)(Xpk + (((o0 + 1) * 1024 + row) << 3)) = u1;
  } else {
    const int m = (b - 1024) * 256 + tid;   // uint slot 0..16383
    const int e0 = m << 1, e1 = e0 + 1;
    const int i0 = ((e0 >> 3) + (e0 & 7)) & NMASK;
    const int i1 = ((e1 >> 3) + (e1 & 7)) & NMASK;
    wlg[m] = (unsigned int)f2bf(W[i0]) | ((unsigned int)f2bf(W[i1]) << 16);
  }
}

// BM=64, BN=128, BK=64. 512 threads = 8 waves: wn = wv&1 (64-col band),
// kb = wv>>1 (k16-quarter of each tile). Wave tile 64x64 (2x2 frags of
// 32x32x16); positional cross-wave LDS reduction at the end.
// MAIN LOOP HAS NO BARRIERS AND NO LDS WRITES:
//   A frags: coalesced global_load_dwordx4 straight from octet-major Xpk
//            (L1/L2-hot; 8KB/tile/block working set), depth-1 reg prefetch.
//   B frags: LDS wl (64 KB, copied once via global_load_lds; read-only;
//            descending-contiguous ds_read_b128 -> conflict-free).
// 16 independent waves/CU hide all latencies by TLP.
__global__ __launch_bounds__(512, 4)
void circ_mm(const unsigned short* __restrict__ Xpk,
             const unsigned short* __restrict__ wlg,
             const float* __restrict__ bias, float* __restrict__ C) {
  extern __shared__ unsigned short smem[];
  unsigned char* __restrict__ sb = (unsigned char*)smem;   // wl: 64 KB

  const int tid = threadIdx.x;
  const int bid = blockIdx.x;
  // XCD-aware mapping: XCD x serves m-panels {x, x+8}; 32 n-tiles share the
  // Xpk panel in that XCD's L2.
  const int x = bid & 7;
  const int i = bid >> 3;
  const int m0 = (x + ((i >> 5) << 3)) << 6;   // 0..960
  const int n0 = (i & 31) << 7;                // 0..3968

  const int lane = tid & 63;
  const int wv = tid >> 6;          // 0..7
  const int wv1024 = wv << 10;

  // ---- async copy wl -> LDS (64 KB = 8 iters x 8 waves x 1 KB) ----
  #pragma unroll
  for (int it = 0; it < 8; ++it) {
    const int b = it * 8192 + wv1024;                  // wave-uniform base
    gload_lds16((const unsigned char*)wlg + b + lane * 16, sb + b);
  }

  // ---- fragment geometry (mfma_f32_32x32x16_bf16) ----
  const int lc = lane & 31;
  const int lh = lane >> 5;
  const int lh8 = lh << 3;
  const int wn = wv & 1;            // 64-col band within block
  const int kb = wv >> 1;           // k16-quarter of each 64-k tile

  // A source: lane reads (row = m0 + mf*32 + lc, oct = t*8 + kb*2 + lh).
  // elem addr = (oct*1024 + row)*8 ; per tile +65536 elems; mf -> +256.
  const unsigned short* gXa =
      Xpk + ((((kb << 1) + lh) << 10) + m0 + lc) * 8;

  int c0f[2];                       // (kb*16 + lh8 - col) & 4095
  #pragma unroll
  for (int nf = 0; nf < 2; ++nf) {
    const int col = n0 + wn * 64 + nf * 32 + lc;
    c0f[nf] = ((kb << 4) + lh8 - col) & NMASK;
  }

  f16v acc[2][2];
  #pragma unroll
  for (int mf = 0; mf < 2; ++mf)
    #pragma unroll
    for (int nf = 0; nf < 2; ++nf)
      #pragma unroll
      for (int e = 0; e < 16; ++e) acc[mf][nf][e] = 0.f;

  // ---- prologue: load tile-0 A frags; wait wl copy ----
  s8v Ac0 = *(const s8v*)(gXa + 0);
  s8v Ac1 = *(const s8v*)(gXa + 256);
  __syncthreads();                  // wl resident (drains vmcnt incl. A loads)

  // ---- main loop: 64 tiles, NO barriers; depth-1 register prefetch ----
  #pragma unroll 2
  for (int t = 0; t < 64; ++t) {
    s8v An0, An1;
    if (t < 63) {                   // issue next-tile A loads
      const unsigned short* gp = gXa + (t + 1) * 65536;
      An0 = *(const s8v*)(gp + 0);
      An1 = *(const s8v*)(gp + 256);
    }

    const int kg = t << 6;
    const int s0 = (kg + c0f[0]) & NMASK;
    const int s1 = (kg + c0f[1]) & NMASK;
    const s8v b0 = *(const s8v*)(sb + (s0 << 4));
    const s8v b1 = *(const s8v*)(sb + (s1 << 4));

    acc[0][0] = __builtin_amdgcn_mfma_f32_32x32x16_bf16(Ac0, b0, acc[0][0], 0, 0, 0);
    acc[1][0] = __builtin_amdgcn_mfma_f32_32x32x16_bf16(Ac1, b0, acc[1][0], 0, 0, 0);
    acc[0][1] = __builtin_amdgcn_mfma_f32_32x32x16_bf16(Ac0, b1, acc[0][1], 0, 0, 0);
    acc[1][1] = __builtin_amdgcn_mfma_f32_32x32x16_bf16(Ac1, b1, acc[1][1], 0, 0, 0);

    Ac0 = An0; Ac1 = An1;
  }

  // ---- epilogue: positional 4-way K reduction (b128), then bias + store ----
  __syncthreads();                  // all waves done reading wl
  float* red = (float*)smem;        // 4 bands x 16 KB = 64 KB (overlays wl)
  float* rb;

  if (kb >= 2) {
    rb = red + ((kb - 2) * 2 + wn) * 4096;
    #pragma unroll
    for (int mf = 0; mf < 2; ++mf)
      #pragma unroll
      for (int nf = 0; nf < 2; ++nf)
        #pragma unroll
        for (int q = 0; q < 4; ++q) {
          const int j = ((mf * 2 + nf) * 4 + q);
          f4v v;
          #pragma unroll
          for (int e = 0; e < 4; ++e) v[e] = acc[mf][nf][q * 4 + e];
          *(f4v*)(&rb[(j * 64 + lane) * 4]) = v;
        }
  }
  __syncthreads();
  if (kb < 2) {
    rb = red + (kb * 2 + wn) * 4096;
    #pragma unroll
    for (int mf = 0; mf < 2; ++mf)
      #pragma unroll
      for (int nf = 0; nf < 2; ++nf)
        #pragma unroll
        for (int q = 0; q < 4; ++q) {
          const int j = ((mf * 2 + nf) * 4 + q);
          const f4v v = *(const f4v*)(&rb[(j * 64 + lane) * 4]);
          #pragma unroll
          for (int e = 0; e < 4; ++e) acc[mf][nf][q * 4 + e] += v[e];
        }
  }
  __syncthreads();
  if (kb == 1) {
    rb = red + wn * 4096;
    #pragma unroll
    for (int mf = 0; mf < 2; ++mf)
      #pragma unroll
      for (int nf = 0; nf < 2; ++nf)
        #pragma unroll
        for (int q = 0; q < 4; ++q) {
          const int j = ((mf * 2 + nf) * 4 + q);
          f4v v;
          #pragma unroll
          for (int e = 0; e < 4; ++e) v[e] = acc[mf][nf][q * 4 + e];
          *(f4v*)(&rb[(j * 64 + lane) * 4]) = v;
        }
  }
  __syncthreads();
  if (kb == 0) {
    rb = red + wn * 4096;
    #pragma unroll
    for (int mf = 0; mf < 2; ++mf)
      #pragma unroll
      for (int nf = 0; nf < 2; ++nf)
        #pragma unroll
        for (int q = 0; q < 4; ++q) {
          const int j = ((mf * 2 + nf) * 4 + q);
          const f4v v = *(const f4v*)(&rb[(j * 64 + lane) * 4]);
          #pragma unroll
          for (int e = 0; e < 4; ++e) acc[mf][nf][q * 4 + e] += v[e];
        }
    const int lh4 = lh << 2;
    #pragma unroll
    for (int nf = 0; nf < 2; ++nf) {
      const int col = n0 + wn * 64 + nf * 32 + lc;
      const float bv = bias[col];
      #pragma unroll
      for (int mf = 0; mf < 2; ++mf)
        #pragma unroll
        for (int g = 0; g < 4; ++g) {
          const int row = m0 + mf * 32 + g * 8 + lh4;
          #pragma unroll
          for (int e = 0; e < 4; ++e)
            C[(row + e) * ND + col] = acc[mf][nf][g * 4 + e] + bv;
        }
    }
  }
}

extern "C" void kernel_launch(void* const* d_in, const int* in_sizes, int n_in,
                              void* d_out, int out_size, void* d_ws, size_t ws_size,
                              hipStream_t stream) {
  (void)hipFuncSetAttribute((const void*)circ_mm,
                            hipFuncAttributeMaxDynamicSharedMemorySize, 65536);
  const float* X    = (const float*)d_in[0];
  const float* W    = (const float*)d_in[1];
  const float* bias = (const float*)d_in[2];
  unsigned short* wlg = (unsigned short*)d_ws;            // 64 KB table
  unsigned short* Xpk = (unsigned short*)d_ws + 32768;    // 8 MB octet-major X

  prep<<<dim3(1088), dim3(256), 0, stream>>>(X, W, Xpk, (unsigned int*)wlg);
  circ_mm<<<dim3(512), dim3(512), 65536, stream>>>(Xpk, wlg, bias, (float*)d_out);
}

// Round 7
// 43.428 us; speedup vs baseline: 1.5007x; 1.0858x over previous
//
#include <hip/hip_runtime.h>

typedef short s8v __attribute__((ext_vector_type(8)));
typedef float f4v __attribute__((ext_vector_type(4)));
typedef float f16v __attribute__((ext_vector_type(16)));

#define ND 4096
#define NMASK 4095

__device__ __forceinline__ unsigned short f2bf(float f) {
  __bf16 h = (__bf16)f;
  return __builtin_bit_cast(unsigned short, h);
}

__device__ __forceinline__ void gload_lds16(const void* g, void* l) {
  __builtin_amdgcn_global_load_lds(
      (const __attribute__((address_space(1))) unsigned int*)g,
      (__attribute__((address_space(3))) unsigned int*)l, 16, 0, 0);
}

// Fused prep:
//  blocks [0,1024):  X f32 -> bf16 in OCTET-MAJOR layout
//                    Xpk[(oct*1024 + row)*8 + j] = bf16(X[row][oct*8+j])
//  blocks [1024,1088): 8-fold sliding-window W table:
//                    wlg[8s+t] = bf16(W[(s+t)&4095])
__global__ __launch_bounds__(256)
void prep(const float* __restrict__ X, const float* __restrict__ W,
          unsigned short* __restrict__ Xpk, unsigned int* __restrict__ wlg) {
  const int b = blockIdx.x;
  const int tid = threadIdx.x;
  if (b < 1024) {
    const int r0 = (b & 15) << 6;        // 64-row band
    const int k0 = (b >> 4) << 6;        // 64-k band
    const int r = tid >> 2;
    const int kseg = tid & 3;            // 16 k each
    const int row = r0 + r;
    const int k = k0 + (kseg << 4);
    const float* src = X + row * ND + k;
    const f4v g0 = *(const f4v*)(src + 0);
    const f4v g1 = *(const f4v*)(src + 4);
    const f4v g2 = *(const f4v*)(src + 8);
    const f4v g3 = *(const f4v*)(src + 12);
    s8v u0, u1;
    #pragma unroll
    for (int j = 0; j < 4; ++j) {
      u0[j] = (short)f2bf(g0[j]); u0[4 + j] = (short)f2bf(g1[j]);
      u1[j] = (short)f2bf(g2[j]); u1[4 + j] = (short)f2bf(g3[j]);
    }
    const int o0 = k >> 3;
    *(s8v*)(Xpk + ((o0 * 1024 + row) << 3))       = u0;
    *(s8v*)(Xpk + (((o0 + 1) * 1024 + row) << 3)) = u1;
  } else {
    const int m = (b - 1024) * 256 + tid;   // uint slot 0..16383
    const int e0 = m << 1, e1 = e0 + 1;
    const int i0 = ((e0 >> 3) + (e0 & 7)) & NMASK;
    const int i1 = ((e1 >> 3) + (e1 & 7)) & NMASK;
    wlg[m] = (unsigned int)f2bf(W[i0]) | ((unsigned int)f2bf(W[i1]) << 16);
  }
}

// BM=64, BN=128, BK=64. 512 threads = 8 waves: wn = wv&1 (64-col band),
// kb = wv>>1 (k16-quarter of each tile). Wave tile 64x64 (2x2 frags of
// 32x32x16); positional cross-wave LDS reduction at the end.
// MAIN LOOP: no barriers, no LDS writes; BOTH operands depth-1 reg-prefetched
// (A via coalesced global_load_dwordx4 from octet-major Xpk; B via
// ds_read_b128 from the read-only wl table) -> no load latency on the
// per-tile critical path. setprio(1) around the MFMA cluster (T5: this
// structure has free-running waves at diverse phases).
__global__ __launch_bounds__(512, 4)
void circ_mm(const unsigned short* __restrict__ Xpk,
             const unsigned short* __restrict__ wlg,
             const float* __restrict__ bias, float* __restrict__ C) {
  extern __shared__ unsigned short smem[];
  unsigned char* __restrict__ sb = (unsigned char*)smem;   // wl: 64 KB

  const int tid = threadIdx.x;
  const int bid = blockIdx.x;
  // XCD-aware mapping: XCD x serves m-panels {x, x+8}; 32 n-tiles share the
  // Xpk panel in that XCD's L2.
  const int x = bid & 7;
  const int i = bid >> 3;
  const int m0 = (x + ((i >> 5) << 3)) << 6;   // 0..960
  const int n0 = (i & 31) << 7;                // 0..3968

  const int lane = tid & 63;
  const int wv = tid >> 6;          // 0..7
  const int wv1024 = wv << 10;

  // ---- async copy wl -> LDS (64 KB = 8 iters x 8 waves x 1 KB) ----
  #pragma unroll
  for (int it = 0; it < 8; ++it) {
    const int b = it * 8192 + wv1024;                  // wave-uniform base
    gload_lds16((const unsigned char*)wlg + b + lane * 16, sb + b);
  }

  // ---- fragment geometry (mfma_f32_32x32x16_bf16) ----
  const int lc = lane & 31;
  const int lh = lane >> 5;
  const int lh8 = lh << 3;
  const int wn = wv & 1;            // 64-col band within block
  const int kb = wv >> 1;           // k16-quarter of each 64-k tile

  // A source: lane reads (row = m0 + mf*32 + lc, oct = t*8 + kb*2 + lh).
  const unsigned short* gXa =
      Xpk + ((((kb << 1) + lh) << 10) + m0 + lc) * 8;

  // B window indices, advanced incrementally by +64 per tile.
  int s0 = ((kb << 4) + lh8 - (n0 + wn * 64 + 0 * 32 + lc)) & NMASK;
  int s1 = ((kb << 4) + lh8 - (n0 + wn * 64 + 1 * 32 + lc)) & NMASK;

  f16v acc[2][2];
  #pragma unroll
  for (int mf = 0; mf < 2; ++mf)
    #pragma unroll
    for (int nf = 0; nf < 2; ++nf)
      #pragma unroll
      for (int e = 0; e < 16; ++e) acc[mf][nf][e] = 0.f;

  // ---- prologue: tile-0 A frags; wl resident; tile-0 B frags ----
  s8v Ac0 = *(const s8v*)(gXa + 0);
  s8v Ac1 = *(const s8v*)(gXa + 256);
  __syncthreads();                  // wl resident (drains vmcnt incl. A loads)
  s8v Bc0 = *(const s8v*)(sb + (s0 << 4));
  s8v Bc1 = *(const s8v*)(sb + (s1 << 4));

  // ---- main loop: 64 tiles, NO barriers; depth-1 prefetch of A and B ----
  #pragma unroll 2
  for (int t = 0; t < 64; ++t) {
    s8v An0, An1, Bn0, Bn1;
    if (t < 63) {                   // issue next-tile loads (A: vmem, B: lds)
      const unsigned short* gp = gXa + (t + 1) * 65536;
      An0 = *(const s8v*)(gp + 0);
      An1 = *(const s8v*)(gp + 256);
      s0 = (s0 + 64) & NMASK;
      s1 = (s1 + 64) & NMASK;
      Bn0 = *(const s8v*)(sb + (s0 << 4));
      Bn1 = *(const s8v*)(sb + (s1 << 4));
    }

    __builtin_amdgcn_s_setprio(1);
    acc[0][0] = __builtin_amdgcn_mfma_f32_32x32x16_bf16(Ac0, Bc0, acc[0][0], 0, 0, 0);
    acc[1][0] = __builtin_amdgcn_mfma_f32_32x32x16_bf16(Ac1, Bc0, acc[1][0], 0, 0, 0);
    acc[0][1] = __builtin_amdgcn_mfma_f32_32x32x16_bf16(Ac0, Bc1, acc[0][1], 0, 0, 0);
    acc[1][1] = __builtin_amdgcn_mfma_f32_32x32x16_bf16(Ac1, Bc1, acc[1][1], 0, 0, 0);
    __builtin_amdgcn_s_setprio(0);

    Ac0 = An0; Ac1 = An1; Bc0 = Bn0; Bc1 = Bn1;
  }

  // ---- epilogue: positional 4-way K reduction (b128), then bias + store ----
  __syncthreads();                  // all waves done reading wl
  float* red = (float*)smem;        // 4 bands x 16 KB = 64 KB (overlays wl)
  float* rb;

  if (kb >= 2) {
    rb = red + ((kb - 2) * 2 + wn) * 4096;
    #pragma unroll
    for (int mf = 0; mf < 2; ++mf)
      #pragma unroll
      for (int nf = 0; nf < 2; ++nf)
        #pragma unroll
        for (int q = 0; q < 4; ++q) {
          const int j = ((mf * 2 + nf) * 4 + q);
          f4v v;
          #pragma unroll
          for (int e = 0; e < 4; ++e) v[e] = acc[mf][nf][q * 4 + e];
          *(f4v*)(&rb[(j * 64 + lane) * 4]) = v;
        }
  }
  __syncthreads();
  if (kb < 2) {
    rb = red + (kb * 2 + wn) * 4096;
    #pragma unroll
    for (int mf = 0; mf < 2; ++mf)
      #pragma unroll
      for (int nf = 0; nf < 2; ++nf)
        #pragma unroll
        for (int q = 0; q < 4; ++q) {
          const int j = ((mf * 2 + nf) * 4 + q);
          const f4v v = *(const f4v*)(&rb[(j * 64 + lane) * 4]);
          #pragma unroll
          for (int e = 0; e < 4; ++e) acc[mf][nf][q * 4 + e] += v[e];
        }
  }
  __syncthreads();
  if (kb == 1) {
    rb = red + wn * 4096;
    #pragma unroll
    for (int mf = 0; mf < 2; ++mf)
      #pragma unroll
      for (int nf = 0; nf < 2; ++nf)
        #pragma unroll
        for (int q = 0; q < 4; ++q) {
          const int j = ((mf * 2 + nf) * 4 + q);
          f4v v;
          #pragma unroll
          for (int e = 0; e < 4; ++e) v[e] = acc[mf][nf][q * 4 + e];
          *(f4v*)(&rb[(j * 64 + lane) * 4]) = v;
        }
  }
  __syncthreads();
  if (kb == 0) {
    rb = red + wn * 4096;
    #pragma unroll
    for (int mf = 0; mf < 2; ++mf)
      #pragma unroll
      for (int nf = 0; nf < 2; ++nf)
        #pragma unroll
        for (int q = 0; q < 4; ++q) {
          const int j = ((mf * 2 + nf) * 4 + q);
          const f4v v = *(const f4v*)(&rb[(j * 64 + lane) * 4]);
          #pragma unroll
          for (int e = 0; e < 4; ++e) acc[mf][nf][q * 4 + e] += v[e];
        }
    const int lh4 = lh << 2;
    #pragma unroll
    for (int nf = 0; nf < 2; ++nf) {
      const int col = n0 + wn * 64 + nf * 32 + lc;
      const float bv = bias[col];
      #pragma unroll
      for (int mf = 0; mf < 2; ++mf)
        #pragma unroll
        for (int g = 0; g < 4; ++g) {
          const int row = m0 + mf * 32 + g * 8 + lh4;
          #pragma unroll
          for (int e = 0; e < 4; ++e)
            C[(row + e) * ND + col] = acc[mf][nf][g * 4 + e] + bv;
        }
    }
  }
}

extern "C" void kernel_launch(void* const* d_in, const int* in_sizes, int n_in,
                              void* d_out, int out_size, void* d_ws, size_t ws_size,
                              hipStream_t stream) {
  (void)hipFuncSetAttribute((const void*)circ_mm,
                            hipFuncAttributeMaxDynamicSharedMemorySize, 65536);
  const float* X    = (const float*)d_in[0];
  const float* W    = (const float*)d_in[1];
  const float* bias = (const float*)d_in[2];
  unsigned short* wlg = (unsigned short*)d_ws;            // 64 KB table
  unsigned short* Xpk = (unsigned short*)d_ws + 32768;    // 8 MB octet-major X

  prep<<<dim3(1088), dim3(256), 0, stream>>>(X, W, Xpk, (unsigned int*)wlg);
  circ_mm<<<dim3(512), dim3(512), 65536, stream>>>(Xpk, wlg, bias, (float*)d_out);
}

// Round 8
// 41.500 us; speedup vs baseline: 1.5704x; 1.0465x over previous
//
#include <hip/hip_runtime.h>

typedef short s8v __attribute__((ext_vector_type(8)));
typedef float f4v __attribute__((ext_vector_type(4)));
typedef float f16v __attribute__((ext_vector_type(16)));

#define ND 4096
#define NMASK 4095

__device__ __forceinline__ unsigned short f2bf(float f) {
  __bf16 h = (__bf16)f;
  return __builtin_bit_cast(unsigned short, h);
}

__device__ __forceinline__ void gload_lds16(const void* g, void* l) {
  __builtin_amdgcn_global_load_lds(
      (const __attribute__((address_space(1))) unsigned int*)g,
      (__attribute__((address_space(3))) unsigned int*)l, 16, 0, 0);
}

// Fused prep:
//  blocks [0,1024):  X f32 -> bf16 in OCTET-MAJOR layout
//                    Xpk[(oct*1024 + row)*8 + j] = bf16(X[row][oct*8+j])
//  blocks [1024,1088): 8-fold sliding-window W table:
//                    wlg[8s+t] = bf16(W[(s+t)&4095])
__global__ __launch_bounds__(256)
void prep(const float* __restrict__ X, const float* __restrict__ W,
          unsigned short* __restrict__ Xpk, unsigned int* __restrict__ wlg) {
  const int b = blockIdx.x;
  const int tid = threadIdx.x;
  if (b < 1024) {
    const int r0 = (b & 15) << 6;        // 64-row band
    const int k0 = (b >> 4) << 6;        // 64-k band
    const int r = tid >> 2;
    const int kseg = tid & 3;            // 16 k each
    const int row = r0 + r;
    const int k = k0 + (kseg << 4);
    const float* src = X + row * ND + k;
    const f4v g0 = *(const f4v*)(src + 0);
    const f4v g1 = *(const f4v*)(src + 4);
    const f4v g2 = *(const f4v*)(src + 8);
    const f4v g3 = *(const f4v*)(src + 12);
    s8v u0, u1;
    #pragma unroll
    for (int j = 0; j < 4; ++j) {
      u0[j] = (short)f2bf(g0[j]); u0[4 + j] = (short)f2bf(g1[j]);
      u1[j] = (short)f2bf(g2[j]); u1[4 + j] = (short)f2bf(g3[j]);
    }
    const int o0 = k >> 3;
    *(s8v*)(Xpk + ((o0 * 1024 + row) << 3))       = u0;
    *(s8v*)(Xpk + (((o0 + 1) * 1024 + row) << 3)) = u1;
  } else {
    const int m = (b - 1024) * 256 + tid;   // uint slot 0..16383
    const int e0 = m << 1, e1 = e0 + 1;
    const int i0 = ((e0 >> 3) + (e0 & 7)) & NMASK;
    const int i1 = ((e1 >> 3) + (e1 & 7)) & NMASK;
    wlg[m] = (unsigned int)f2bf(W[i0]) | ((unsigned int)f2bf(W[i1]) << 16);
  }
}

// BM=64, BN=128, BK=64. 256 threads = 4 waves, kb = wv (K-quarter ONLY --
// no n-split). Each wave computes the FULL 64x128 block tile (2x4 frags of
// 32x32x16) over its K-quarter; 4-way positional LDS reduction at the end.
// Per tile per wave: 2 A-reads feed 8 MFMAs (A bytes/MFMA = 256B, half of
// the Nf=2 scheme) -> L1 port (64B/cy) drops below the matrix pipe; matrix
// is the single binding resource.
// MAIN LOOP: no barriers, no LDS writes; A and B depth-1 reg-prefetched.
__global__ __launch_bounds__(256, 2)
void circ_mm(const unsigned short* __restrict__ Xpk,
             const unsigned short* __restrict__ wlg,
             const float* __restrict__ bias, float* __restrict__ C) {
  extern __shared__ unsigned short smem[];
  unsigned char* __restrict__ sb = (unsigned char*)smem;   // wl: 64 KB

  const int tid = threadIdx.x;
  const int bid = blockIdx.x;
  // XCD-aware mapping: XCD x serves m-panels {x, x+8}; 32 n-tiles share the
  // Xpk panel in that XCD's L2.
  const int x = bid & 7;
  const int i = bid >> 3;
  const int m0 = (x + ((i >> 5) << 3)) << 6;   // 0..960
  const int n0 = (i & 31) << 7;                // 0..3968

  const int lane = tid & 63;
  const int wv = tid >> 6;          // 0..3
  const int kb = wv;                // k16-quarter of each 64-k tile

  // ---- async copy wl -> LDS (64 KB = 16 iters x 4 waves x 1 KB) ----
  #pragma unroll
  for (int it = 0; it < 16; ++it) {
    const int b = it * 4096 + (wv << 10);              // wave-uniform base
    gload_lds16((const unsigned char*)wlg + b + lane * 16, sb + b);
  }

  // ---- fragment geometry (mfma_f32_32x32x16_bf16) ----
  const int lc = lane & 31;
  const int lh = lane >> 5;
  const int lh8 = lh << 3;

  // A source: lane reads (row = m0 + mf*32 + lc, oct = t*8 + kb*2 + lh).
  const unsigned short* gXa =
      Xpk + ((((kb << 1) + lh) << 10) + m0 + lc) * 8;

  // B window indices (one per n-frag), advanced incrementally +64/tile.
  int s0 = ((kb << 4) + lh8 - (n0 + 0 * 32 + lc)) & NMASK;
  int s1 = ((kb << 4) + lh8 - (n0 + 1 * 32 + lc)) & NMASK;
  int s2 = ((kb << 4) + lh8 - (n0 + 2 * 32 + lc)) & NMASK;
  int s3 = ((kb << 4) + lh8 - (n0 + 3 * 32 + lc)) & NMASK;

  f16v acc[2][4];
  #pragma unroll
  for (int mf = 0; mf < 2; ++mf)
    #pragma unroll
    for (int nf = 0; nf < 4; ++nf)
      #pragma unroll
      for (int e = 0; e < 16; ++e) acc[mf][nf][e] = 0.f;

  // ---- prologue: tile-0 A frags; wl resident; tile-0 B frags ----
  s8v Ac0 = *(const s8v*)(gXa + 0);
  s8v Ac1 = *(const s8v*)(gXa + 256);
  __syncthreads();                  // wl resident (drains vmcnt incl. A loads)
  s8v Bc0 = *(const s8v*)(sb + (s0 << 4));
  s8v Bc1 = *(const s8v*)(sb + (s1 << 4));
  s8v Bc2 = *(const s8v*)(sb + (s2 << 4));
  s8v Bc3 = *(const s8v*)(sb + (s3 << 4));

  // ---- main loop: 64 tiles, NO barriers; depth-1 prefetch of A and B ----
  #pragma unroll 2
  for (int t = 0; t < 64; ++t) {
    s8v An0, An1, Bn0, Bn1, Bn2, Bn3;
    if (t < 63) {                   // issue next-tile loads (A: vmem, B: lds)
      const unsigned short* gp = gXa + (t + 1) * 65536;
      An0 = *(const s8v*)(gp + 0);
      An1 = *(const s8v*)(gp + 256);
      s0 = (s0 + 64) & NMASK;
      s1 = (s1 + 64) & NMASK;
      s2 = (s2 + 64) & NMASK;
      s3 = (s3 + 64) & NMASK;
      Bn0 = *(const s8v*)(sb + (s0 << 4));
      Bn1 = *(const s8v*)(sb + (s1 << 4));
      Bn2 = *(const s8v*)(sb + (s2 << 4));
      Bn3 = *(const s8v*)(sb + (s3 << 4));
    }

    __builtin_amdgcn_s_setprio(1);
    acc[0][0] = __builtin_amdgcn_mfma_f32_32x32x16_bf16(Ac0, Bc0, acc[0][0], 0, 0, 0);
    acc[1][0] = __builtin_amdgcn_mfma_f32_32x32x16_bf16(Ac1, Bc0, acc[1][0], 0, 0, 0);
    acc[0][1] = __builtin_amdgcn_mfma_f32_32x32x16_bf16(Ac0, Bc1, acc[0][1], 0, 0, 0);
    acc[1][1] = __builtin_amdgcn_mfma_f32_32x32x16_bf16(Ac1, Bc1, acc[1][1], 0, 0, 0);
    acc[0][2] = __builtin_amdgcn_mfma_f32_32x32x16_bf16(Ac0, Bc2, acc[0][2], 0, 0, 0);
    acc[1][2] = __builtin_amdgcn_mfma_f32_32x32x16_bf16(Ac1, Bc2, acc[1][2], 0, 0, 0);
    acc[0][3] = __builtin_amdgcn_mfma_f32_32x32x16_bf16(Ac0, Bc3, acc[0][3], 0, 0, 0);
    acc[1][3] = __builtin_amdgcn_mfma_f32_32x32x16_bf16(Ac1, Bc3, acc[1][3], 0, 0, 0);
    __builtin_amdgcn_s_setprio(0);

    Ac0 = An0; Ac1 = An1;
    Bc0 = Bn0; Bc1 = Bn1; Bc2 = Bn2; Bc3 = Bn3;
  }

  // ---- epilogue: positional 4-way K reduction (b128), then bias + store ----
  // All kb waves share the same (lane, mf, nf, e) -> (row, col) map, so the
  // exchange is positional: chunk j = (mf*4+nf)*4+q at red[band][(j*64+l)*4].
  __syncthreads();                  // all waves done reading wl
  float* red = (float*)smem;        // 2 bands x 32 KB = 64 KB (overlays wl)
  float* rb;

  if (kb >= 2) {
    rb = red + (kb - 2) * 8192;
    #pragma unroll
    for (int mf = 0; mf < 2; ++mf)
      #pragma unroll
      for (int nf = 0; nf < 4; ++nf)
        #pragma unroll
        for (int q = 0; q < 4; ++q) {
          const int j = (mf * 4 + nf) * 4 + q;
          f4v v;
          #pragma unroll
          for (int e = 0; e < 4; ++e) v[e] = acc[mf][nf][q * 4 + e];
          *(f4v*)(&rb[(j * 64 + lane) * 4]) = v;
        }
  }
  __syncthreads();
  if (kb < 2) {
    rb = red + kb * 8192;
    #pragma unroll
    for (int mf = 0; mf < 2; ++mf)
      #pragma unroll
      for (int nf = 0; nf < 4; ++nf)
        #pragma unroll
        for (int q = 0; q < 4; ++q) {
          const int j = (mf * 4 + nf) * 4 + q;
          const f4v v = *(const f4v*)(&rb[(j * 64 + lane) * 4]);
          #pragma unroll
          for (int e = 0; e < 4; ++e) acc[mf][nf][q * 4 + e] += v[e];
        }
  }
  __syncthreads();
  if (kb == 1) {
    rb = red;
    #pragma unroll
    for (int mf = 0; mf < 2; ++mf)
      #pragma unroll
      for (int nf = 0; nf < 4; ++nf)
        #pragma unroll
        for (int q = 0; q < 4; ++q) {
          const int j = (mf * 4 + nf) * 4 + q;
          f4v v;
          #pragma unroll
          for (int e = 0; e < 4; ++e) v[e] = acc[mf][nf][q * 4 + e];
          *(f4v*)(&rb[(j * 64 + lane) * 4]) = v;
        }
  }
  __syncthreads();
  if (kb == 0) {
    rb = red;
    #pragma unroll
    for (int mf = 0; mf < 2; ++mf)
      #pragma unroll
      for (int nf = 0; nf < 4; ++nf)
        #pragma unroll
        for (int q = 0; q < 4; ++q) {
          const int j = (mf * 4 + nf) * 4 + q;
          const f4v v = *(const f4v*)(&rb[(j * 64 + lane) * 4]);
          #pragma unroll
          for (int e = 0; e < 4; ++e) acc[mf][nf][q * 4 + e] += v[e];
        }
    const int lh4 = lh << 2;
    #pragma unroll
    for (int nf = 0; nf < 4; ++nf) {
      const int col = n0 + nf * 32 + lc;
      const float bv = bias[col];
      #pragma unroll
      for (int mf = 0; mf < 2; ++mf)
        #pragma unroll
        for (int g = 0; g < 4; ++g) {
          const int row = m0 + mf * 32 + g * 8 + lh4;
          #pragma unroll
          for (int e = 0; e < 4; ++e)
            C[(row + e) * ND + col] = acc[mf][nf][g * 4 + e] + bv;
        }
    }
  }
}

extern "C" void kernel_launch(void* const* d_in, const int* in_sizes, int n_in,
                              void* d_out, int out_size, void* d_ws, size_t ws_size,
                              hipStream_t stream) {
  (void)hipFuncSetAttribute((const void*)circ_mm,
                            hipFuncAttributeMaxDynamicSharedMemorySize, 65536);
  const float* X    = (const float*)d_in[0];
  const float* W    = (const float*)d_in[1];
  const float* bias = (const float*)d_in[2];
  unsigned short* wlg = (unsigned short*)d_ws;            // 64 KB table
  unsigned short* Xpk = (unsigned short*)d_ws + 32768;    // 8 MB octet-major X

  prep<<<dim3(1088), dim3(256), 0, stream>>>(X, W, Xpk, (unsigned int*)wlg);
  circ_mm<<<dim3(512), dim3(256), 65536, stream>>>(Xpk, wlg, bias, (float*)d_out);
}

// Round 9
// 40.306 us; speedup vs baseline: 1.6169x; 1.0296x over previous
//
#include <hip/hip_runtime.h>

typedef short s8v __attribute__((ext_vector_type(8)));
typedef float f4v __attribute__((ext_vector_type(4)));
typedef float f16v __attribute__((ext_vector_type(16)));

#define ND 4096
#define NMASK 4095

__device__ __forceinline__ unsigned short f2bf(float f) {
  __bf16 h = (__bf16)f;
  return __builtin_bit_cast(unsigned short, h);
}

__device__ __forceinline__ void gload_lds16(const void* g, void* l) {
  __builtin_amdgcn_global_load_lds(
      (const __attribute__((address_space(1))) unsigned int*)g,
      (__attribute__((address_space(3))) unsigned int*)l, 16, 0, 0);
}

// Fused prep:
//  blocks [0,1024):  X f32 -> bf16 in OCTET-MAJOR layout
//                    Xpk[(oct*1024 + row)*8 + j] = bf16(X[row][oct*8+j])
//  blocks [1024,1088): 8-fold sliding-window W table:
//                    wlg[8s+t] = bf16(W[(s+t)&4095])
__global__ __launch_bounds__(256)
void prep(const float* __restrict__ X, const float* __restrict__ W,
          unsigned short* __restrict__ Xpk, unsigned int* __restrict__ wlg) {
  const int b = blockIdx.x;
  const int tid = threadIdx.x;
  if (b < 1024) {
    const int r0 = (b & 15) << 6;        // 64-row band
    const int k0 = (b >> 4) << 6;        // 64-k band
    const int r = tid >> 2;
    const int kseg = tid & 3;            // 16 k each
    const int row = r0 + r;
    const int k = k0 + (kseg << 4);
    const float* src = X + row * ND + k;
    const f4v g0 = *(const f4v*)(src + 0);
    const f4v g1 = *(const f4v*)(src + 4);
    const f4v g2 = *(const f4v*)(src + 8);
    const f4v g3 = *(const f4v*)(src + 12);
    s8v u0, u1;
    #pragma unroll
    for (int j = 0; j < 4; ++j) {
      u0[j] = (short)f2bf(g0[j]); u0[4 + j] = (short)f2bf(g1[j]);
      u1[j] = (short)f2bf(g2[j]); u1[4 + j] = (short)f2bf(g3[j]);
    }
    const int o0 = k >> 3;
    *(s8v*)(Xpk + ((o0 * 1024 + row) << 3))       = u0;
    *(s8v*)(Xpk + (((o0 + 1) * 1024 + row) << 3)) = u1;
  } else {
    const int m = (b - 1024) * 256 + tid;   // uint slot 0..16383
    const int e0 = m << 1, e1 = e0 + 1;
    const int i0 = ((e0 >> 3) + (e0 & 7)) & NMASK;
    const int i1 = ((e1 >> 3) + (e1 & 7)) & NMASK;
    wlg[m] = (unsigned int)f2bf(W[i0]) | ((unsigned int)f2bf(W[i1]) << 16);
  }
}

// BM=64, BN=128, BK=64. 256 threads = 4 waves, kb = wv (pure K-split).
// Each wave computes the FULL 64x128 block tile (2x4 frags of 32x32x16)
// over its K-quarter; 4-way positional LDS reduction at the end.
// MAIN LOOP: FULLY UNROLLED (64 tiles), branch-free steady state.
//   A: depth-2 register prefetch, 3-buffer rotation (cover ~2 tile periods
//      -> L2 latency off the path even when waves lockstep on the shared
//      matrix pipe).
//   B: depth-1, 2-buffer rotation (LDS latency ~150cy, 1 tile covers it).
// All rotation indices are compile-time (full unroll) -> registers.
__global__ __launch_bounds__(256, 2)
void circ_mm(const unsigned short* __restrict__ Xpk,
             const unsigned short* __restrict__ wlg,
             const float* __restrict__ bias, float* __restrict__ C) {
  extern __shared__ unsigned short smem[];
  unsigned char* __restrict__ sb = (unsigned char*)smem;   // wl: 64 KB

  const int tid = threadIdx.x;
  const int bid = blockIdx.x;
  // XCD-aware mapping: XCD x serves m-panels {x, x+8}; 32 n-tiles share the
  // Xpk panel in that XCD's L2.
  const int x = bid & 7;
  const int i = bid >> 3;
  const int m0 = (x + ((i >> 5) << 3)) << 6;   // 0..960
  const int n0 = (i & 31) << 7;                // 0..3968

  const int lane = tid & 63;
  const int wv = tid >> 6;          // 0..3
  const int kb = wv;                // k16-quarter of each 64-k tile

  // ---- async copy wl -> LDS (64 KB = 16 iters x 4 waves x 1 KB) ----
  #pragma unroll
  for (int it = 0; it < 16; ++it) {
    const int b = it * 4096 + (wv << 10);              // wave-uniform base
    gload_lds16((const unsigned char*)wlg + b + lane * 16, sb + b);
  }

  // ---- fragment geometry (mfma_f32_32x32x16_bf16) ----
  const int lc = lane & 31;
  const int lh = lane >> 5;
  const int lh8 = lh << 3;

  // A source: lane reads (row = m0 + mf*32 + lc, oct = t*8 + kb*2 + lh).
  const unsigned short* gXa =
      Xpk + ((((kb << 1) + lh) << 10) + m0 + lc) * 8;

  // B window indices (one per n-frag), advanced incrementally +64/tile.
  int s0 = ((kb << 4) + lh8 - (n0 + 0 * 32 + lc)) & NMASK;
  int s1 = ((kb << 4) + lh8 - (n0 + 1 * 32 + lc)) & NMASK;
  int s2 = ((kb << 4) + lh8 - (n0 + 2 * 32 + lc)) & NMASK;
  int s3 = ((kb << 4) + lh8 - (n0 + 3 * 32 + lc)) & NMASK;

  f16v acc[2][4];
  #pragma unroll
  for (int mf = 0; mf < 2; ++mf)
    #pragma unroll
    for (int nf = 0; nf < 4; ++nf)
      #pragma unroll
      for (int e = 0; e < 16; ++e) acc[mf][nf][e] = 0.f;

  s8v Ab[3][2];                     // 3-buffer A rotation (depth-2)
  s8v Bb[2][4];                     // 2-buffer B rotation (depth-1)

  // ---- prologue: issue A(0),A(1); wl resident; read B(0) ----
  Ab[0][0] = *(const s8v*)(gXa + 0);
  Ab[0][1] = *(const s8v*)(gXa + 256);
  Ab[1][0] = *(const s8v*)(gXa + 65536);
  Ab[1][1] = *(const s8v*)(gXa + 65536 + 256);
  __syncthreads();                  // wl resident (drains vmcnt incl. A loads)
  Bb[0][0] = *(const s8v*)(sb + (s0 << 4));
  Bb[0][1] = *(const s8v*)(sb + (s1 << 4));
  Bb[0][2] = *(const s8v*)(sb + (s2 << 4));
  Bb[0][3] = *(const s8v*)(sb + (s3 << 4));

  // ---- main loop: fully unrolled; A issue-distance 2, B issue-distance 1 ----
  #pragma unroll
  for (int t = 0; t < 64; ++t) {
    if (t + 2 < 64) {               // compile-time condition
      const unsigned short* gp = gXa + (t + 2) * 65536;
      Ab[(t + 2) % 3][0] = *(const s8v*)(gp + 0);
      Ab[(t + 2) % 3][1] = *(const s8v*)(gp + 256);
    }
    if (t + 1 < 64) {               // compile-time condition
      s0 = (s0 + 64) & NMASK;
      s1 = (s1 + 64) & NMASK;
      s2 = (s2 + 64) & NMASK;
      s3 = (s3 + 64) & NMASK;
      Bb[(t + 1) & 1][0] = *(const s8v*)(sb + (s0 << 4));
      Bb[(t + 1) & 1][1] = *(const s8v*)(sb + (s1 << 4));
      Bb[(t + 1) & 1][2] = *(const s8v*)(sb + (s2 << 4));
      Bb[(t + 1) & 1][3] = *(const s8v*)(sb + (s3 << 4));
    }

    const s8v a0 = Ab[t % 3][0];
    const s8v a1 = Ab[t % 3][1];
    __builtin_amdgcn_s_setprio(1);
    acc[0][0] = __builtin_amdgcn_mfma_f32_32x32x16_bf16(a0, Bb[t & 1][0], acc[0][0], 0, 0, 0);
    acc[1][0] = __builtin_amdgcn_mfma_f32_32x32x16_bf16(a1, Bb[t & 1][0], acc[1][0], 0, 0, 0);
    acc[0][1] = __builtin_amdgcn_mfma_f32_32x32x16_bf16(a0, Bb[t & 1][1], acc[0][1], 0, 0, 0);
    acc[1][1] = __builtin_amdgcn_mfma_f32_32x32x16_bf16(a1, Bb[t & 1][1], acc[1][1], 0, 0, 0);
    acc[0][2] = __builtin_amdgcn_mfma_f32_32x32x16_bf16(a0, Bb[t & 1][2], acc[0][2], 0, 0, 0);
    acc[1][2] = __builtin_amdgcn_mfma_f32_32x32x16_bf16(a1, Bb[t & 1][2], acc[1][2], 0, 0, 0);
    acc[0][3] = __builtin_amdgcn_mfma_f32_32x32x16_bf16(a0, Bb[t & 1][3], acc[0][3], 0, 0, 0);
    acc[1][3] = __builtin_amdgcn_mfma_f32_32x32x16_bf16(a1, Bb[t & 1][3], acc[1][3], 0, 0, 0);
    __builtin_amdgcn_s_setprio(0);
  }

  // ---- epilogue: positional 4-way K reduction (b128), then bias + store ----
  __syncthreads();                  // all waves done reading wl
  float* red = (float*)smem;        // 2 bands x 32 KB = 64 KB (overlays wl)
  float* rb;

  if (kb >= 2) {
    rb = red + (kb - 2) * 8192;
    #pragma unroll
    for (int mf = 0; mf < 2; ++mf)
      #pragma unroll
      for (int nf = 0; nf < 4; ++nf)
        #pragma unroll
        for (int q = 0; q < 4; ++q) {
          const int j = (mf * 4 + nf) * 4 + q;
          f4v v;
          #pragma unroll
          for (int e = 0; e < 4; ++e) v[e] = acc[mf][nf][q * 4 + e];
          *(f4v*)(&rb[(j * 64 + lane) * 4]) = v;
        }
  }
  __syncthreads();
  if (kb < 2) {
    rb = red + kb * 8192;
    #pragma unroll
    for (int mf = 0; mf < 2; ++mf)
      #pragma unroll
      for (int nf = 0; nf < 4; ++nf)
        #pragma unroll
        for (int q = 0; q < 4; ++q) {
          const int j = (mf * 4 + nf) * 4 + q;
          const f4v v = *(const f4v*)(&rb[(j * 64 + lane) * 4]);
          #pragma unroll
          for (int e = 0; e < 4; ++e) acc[mf][nf][q * 4 + e] += v[e];
        }
  }
  __syncthreads();
  if (kb == 1) {
    rb = red;
    #pragma unroll
    for (int mf = 0; mf < 2; ++mf)
      #pragma unroll
      for (int nf = 0; nf < 4; ++nf)
        #pragma unroll
        for (int q = 0; q < 4; ++q) {
          const int j = (mf * 4 + nf) * 4 + q;
          f4v v;
          #pragma unroll
          for (int e = 0; e < 4; ++e) v[e] = acc[mf][nf][q * 4 + e];
          *(f4v*)(&rb[(j * 64 + lane) * 4]) = v;
        }
  }
  __syncthreads();
  if (kb == 0) {
    rb = red;
    #pragma unroll
    for (int mf = 0; mf < 2; ++mf)
      #pragma unroll
      for (int nf = 0; nf < 4; ++nf)
        #pragma unroll
        for (int q = 0; q < 4; ++q) {
          const int j = (mf * 4 + nf) * 4 + q;
          const f4v v = *(const f4v*)(&rb[(j * 64 + lane) * 4]);
          #pragma unroll
          for (int e = 0; e < 4; ++e) acc[mf][nf][q * 4 + e] += v[e];
        }
    const int lh4 = lh << 2;
    #pragma unroll
    for (int nf = 0; nf < 4; ++nf) {
      const int col = n0 + nf * 32 + lc;
      const float bv = bias[col];
      #pragma unroll
      for (int mf = 0; mf < 2; ++mf)
        #pragma unroll
        for (int g = 0; g < 4; ++g) {
          const int row = m0 + mf * 32 + g * 8 + lh4;
          #pragma unroll
          for (int e = 0; e < 4; ++e)
            C[(row + e) * ND + col] = acc[mf][nf][g * 4 + e] + bv;
        }
    }
  }
}

extern "C" void kernel_launch(void* const* d_in, const int* in_sizes, int n_in,
                              void* d_out, int out_size, void* d_ws, size_t ws_size,
                              hipStream_t stream) {
  (void)hipFuncSetAttribute((const void*)circ_mm,
                            hipFuncAttributeMaxDynamicSharedMemorySize, 65536);
  const float* X    = (const float*)d_in[0];
  const float* W    = (const float*)d_in[1];
  const float* bias = (const float*)d_in[2];
  unsigned short* wlg = (unsigned short*)d_ws;            // 64 KB table
  unsigned short* Xpk = (unsigned short*)d_ws + 32768;    // 8 MB octet-major X

  prep<<<dim3(1088), dim3(256), 0, stream>>>(X, W, Xpk, (unsigned int*)wlg);
  circ_mm<<<dim3(512), dim3(256), 65536, stream>>>(Xpk, wlg, bias, (float*)d_out);
}

// Round 11
// 39.320 us; speedup vs baseline: 1.6575x; 1.0251x over previous
//
#include <hip/hip_runtime.h>

typedef short s8v __attribute__((ext_vector_type(8)));
typedef float f4v __attribute__((ext_vector_type(4)));
typedef float f16v __attribute__((ext_vector_type(16)));

#define ND 4096
#define NMASK 4095

__device__ __forceinline__ unsigned short f2bf(float f) {
  __bf16 h = (__bf16)f;
  return __builtin_bit_cast(unsigned short, h);
}

__device__ __forceinline__ void gload_lds16(const void* g, void* l) {
  __builtin_amdgcn_global_load_lds(
      (const __attribute__((address_space(1))) unsigned int*)g,
      (__attribute__((address_space(3))) unsigned int*)l, 16, 0, 0);
}

// Fused prep:
//  blocks [0,1024):  X f32 -> bf16 in OCTET-MAJOR layout
//                    Xpk[(oct*1024 + row)*8 + j] = bf16(X[row][oct*8+j])
//  blocks [1024,1088): 8-fold sliding-window W table:
//                    wlg[8s+t] = bf16(W[(s+t)&4095])
__global__ __launch_bounds__(256)
void prep(const float* __restrict__ X, const float* __restrict__ W,
          unsigned short* __restrict__ Xpk, unsigned int* __restrict__ wlg) {
  const int b = blockIdx.x;
  const int tid = threadIdx.x;
  if (b < 1024) {
    const int r0 = (b & 15) << 6;        // 64-row band
    const int k0 = (b >> 4) << 6;        // 64-k band
    const int r = tid >> 2;
    const int kseg = tid & 3;            // 16 k each
    const int row = r0 + r;
    const int k = k0 + (kseg << 4);
    const float* src = X + row * ND + k;
    const f4v g0 = *(const f4v*)(src + 0);
    const f4v g1 = *(const f4v*)(src + 4);
    const f4v g2 = *(const f4v*)(src + 8);
    const f4v g3 = *(const f4v*)(src + 12);
    s8v u0, u1;
    #pragma unroll
    for (int j = 0; j < 4; ++j) {
      u0[j] = (short)f2bf(g0[j]); u0[4 + j] = (short)f2bf(g1[j]);
      u1[j] = (short)f2bf(g2[j]); u1[4 + j] = (short)f2bf(g3[j]);
    }
    const int o0 = k >> 3;
    *(s8v*)(Xpk + ((o0 * 1024 + row) << 3))       = u0;
    *(s8v*)(Xpk + (((o0 + 1) * 1024 + row) << 3)) = u1;
  } else {
    const int m = (b - 1024) * 256 + tid;   // uint slot 0..16383
    const int e0 = m << 1, e1 = e0 + 1;
    const int i0 = ((e0 >> 3) + (e0 & 7)) & NMASK;
    const int i1 = ((e1 >> 3) + (e1 & 7)) & NMASK;
    wlg[m] = (unsigned int)f2bf(W[i0]) | ((unsigned int)f2bf(W[i1]) << 16);
  }
}

// BM=64, BN=128, BK=64. 256 threads = 4 waves, kb = wv (pure K-split).
// Each wave computes the FULL 64x128 block tile (2x4 frags of 32x32x16)
// over its K-quarter. MAIN LOOP: fully unrolled, branch-free; A depth-2
// (3-buffer), B depth-1 (2-buffer); no barriers, no LDS writes.
// EPILOGUE: positional reduction where every wave ends with a QUARTER of
// the final sum and stores it (4x store parallelism, 3 barriers).
__global__ __launch_bounds__(256, 2)
void circ_mm(const unsigned short* __restrict__ Xpk,
             const unsigned short* __restrict__ wlg,
             const float* __restrict__ bias, float* __restrict__ C) {
  extern __shared__ unsigned short smem[];
  unsigned char* __restrict__ sb = (unsigned char*)smem;   // wl: 64 KB

  const int tid = threadIdx.x;
  const int bid = blockIdx.x;
  // XCD-aware mapping: XCD x serves m-panels {x, x+8}; 32 n-tiles share the
  // Xpk panel in that XCD's L2.
  const int x = bid & 7;
  const int i = bid >> 3;
  const int m0 = (x + ((i >> 5) << 3)) << 6;   // 0..960
  const int n0 = (i & 31) << 7;                // 0..3968

  const int lane = tid & 63;
  const int wv = tid >> 6;          // 0..3
  const int kb = wv;                // k16-quarter of each 64-k tile

  // ---- async copy wl -> LDS (64 KB = 16 iters x 4 waves x 1 KB) ----
  #pragma unroll
  for (int it = 0; it < 16; ++it) {
    const int b = it * 4096 + (wv << 10);              // wave-uniform base
    gload_lds16((const unsigned char*)wlg + b + lane * 16, sb + b);
  }

  // ---- fragment geometry (mfma_f32_32x32x16_bf16) ----
  const int lc = lane & 31;
  const int lh = lane >> 5;
  const int lh8 = lh << 3;

  // A source: lane reads (row = m0 + mf*32 + lc, oct = t*8 + kb*2 + lh).
  const unsigned short* gXa =
      Xpk + ((((kb << 1) + lh) << 10) + m0 + lc) * 8;

  // B window indices (one per n-frag), advanced incrementally +64/tile.
  int s0 = ((kb << 4) + lh8 - (n0 + 0 * 32 + lc)) & NMASK;
  int s1 = ((kb << 4) + lh8 - (n0 + 1 * 32 + lc)) & NMASK;
  int s2 = ((kb << 4) + lh8 - (n0 + 2 * 32 + lc)) & NMASK;
  int s3 = ((kb << 4) + lh8 - (n0 + 3 * 32 + lc)) & NMASK;

  f16v acc[2][4];
  #pragma unroll
  for (int mf = 0; mf < 2; ++mf)
    #pragma unroll
    for (int nf = 0; nf < 4; ++nf)
      #pragma unroll
      for (int e = 0; e < 16; ++e) acc[mf][nf][e] = 0.f;

  s8v Ab[3][2];                     // 3-buffer A rotation (depth-2)
  s8v Bb[2][4];                     // 2-buffer B rotation (depth-1)

  // ---- prologue: issue A(0),A(1); wl resident; read B(0) ----
  Ab[0][0] = *(const s8v*)(gXa + 0);
  Ab[0][1] = *(const s8v*)(gXa + 256);
  Ab[1][0] = *(const s8v*)(gXa + 65536);
  Ab[1][1] = *(const s8v*)(gXa + 65536 + 256);
  __syncthreads();                  // wl resident (drains vmcnt incl. A loads)
  Bb[0][0] = *(const s8v*)(sb + (s0 << 4));
  Bb[0][1] = *(const s8v*)(sb + (s1 << 4));
  Bb[0][2] = *(const s8v*)(sb + (s2 << 4));
  Bb[0][3] = *(const s8v*)(sb + (s3 << 4));

  // ---- main loop: fully unrolled; A issue-distance 2, B issue-distance 1 ----
  #pragma unroll
  for (int t = 0; t < 64; ++t) {
    if (t + 2 < 64) {               // compile-time condition
      const unsigned short* gp = gXa + (t + 2) * 65536;
      Ab[(t + 2) % 3][0] = *(const s8v*)(gp + 0);
      Ab[(t + 2) % 3][1] = *(const s8v*)(gp + 256);
    }
    if (t + 1 < 64) {               // compile-time condition
      s0 = (s0 + 64) & NMASK;
      s1 = (s1 + 64) & NMASK;
      s2 = (s2 + 64) & NMASK;
      s3 = (s3 + 64) & NMASK;
      Bb[(t + 1) & 1][0] = *(const s8v*)(sb + (s0 << 4));
      Bb[(t + 1) & 1][1] = *(const s8v*)(sb + (s1 << 4));
      Bb[(t + 1) & 1][2] = *(const s8v*)(sb + (s2 << 4));
      Bb[(t + 1) & 1][3] = *(const s8v*)(sb + (s3 << 4));
    }

    const s8v a0 = Ab[t % 3][0];
    const s8v a1 = Ab[t % 3][1];
    __builtin_amdgcn_s_setprio(1);
    acc[0][0] = __builtin_amdgcn_mfma_f32_32x32x16_bf16(a0, Bb[t & 1][0], acc[0][0], 0, 0, 0);
    acc[1][0] = __builtin_amdgcn_mfma_f32_32x32x16_bf16(a1, Bb[t & 1][0], acc[1][0], 0, 0, 0);
    acc[0][1] = __builtin_amdgcn_mfma_f32_32x32x16_bf16(a0, Bb[t & 1][1], acc[0][1], 0, 0, 0);
    acc[1][1] = __builtin_amdgcn_mfma_f32_32x32x16_bf16(a1, Bb[t & 1][1], acc[1][1], 0, 0, 0);
    acc[0][2] = __builtin_amdgcn_mfma_f32_32x32x16_bf16(a0, Bb[t & 1][2], acc[0][2], 0, 0, 0);
    acc[1][2] = __builtin_amdgcn_mfma_f32_32x32x16_bf16(a1, Bb[t & 1][2], acc[1][2], 0, 0, 0);
    acc[0][3] = __builtin_amdgcn_mfma_f32_32x32x16_bf16(a0, Bb[t & 1][3], acc[0][3], 0, 0, 0);
    acc[1][3] = __builtin_amdgcn_mfma_f32_32x32x16_bf16(a1, Bb[t & 1][3], acc[1][3], 0, 0, 0);
    __builtin_amdgcn_s_setprio(0);
  }

  // ---- epilogue: all-wave positional reduction, 3 barriers ----
  // chunk j = (mf*4+nf)*4+q, j in [0,32); element access by VALUE (vector
  // subscript with compile-time index -> registers; &vec[e] is illegal).
  #define ACC_EL(j, e) (acc[(j) >> 4][((j) >> 2) & 3][((j) & 3) * 4 + (e)])

  __syncthreads();                  // main-loop wl reads done (overlays wl)
  float* red = (float*)smem;        // band0 = red[0..8192), band1 = +8192

  // step 1: kb2/kb3 dump full acc; kb0/kb1 accumulate
  if (kb == 2 || kb == 3) {
    float* rb = red + (kb - 2) * 8192;
    #pragma unroll
    for (int j = 0; j < 32; ++j) {
      f4v v;
      #pragma unroll
      for (int e = 0; e < 4; ++e) v[e] = ACC_EL(j, e);
      *(f4v*)(&rb[(j * 64 + lane) * 4]) = v;
    }
  }
  __syncthreads();
  if (kb == 0) {
    float* rb = red;                // band0: sum02 = acc + kb2
    #pragma unroll
    for (int j = 0; j < 32; ++j) {
      const f4v v = *(const f4v*)(&rb[(j * 64 + lane) * 4]);
      #pragma unroll
      for (int e = 0; e < 4; ++e) ACC_EL(j, e) += v[e];
    }
    #pragma unroll
    for (int j = 8; j < 32; ++j) {  // publish chunks 8..31
      f4v v;
      #pragma unroll
      for (int e = 0; e < 4; ++e) v[e] = ACC_EL(j, e);
      *(f4v*)(&rb[(j * 64 + lane) * 4]) = v;
    }
  }
  if (kb == 1) {
    float* rb = red + 8192;         // band1: sum13 = acc + kb3
    #pragma unroll
    for (int j = 0; j < 32; ++j) {
      const f4v v = *(const f4v*)(&rb[(j * 64 + lane) * 4]);
      #pragma unroll
      for (int e = 0; e < 4; ++e) ACC_EL(j, e) += v[e];
    }
    #pragma unroll
    for (int j = 0; j < 8; ++j) {   // publish chunks 0..7
      f4v v;
      #pragma unroll
      for (int e = 0; e < 4; ++e) v[e] = ACC_EL(j, e);
      *(f4v*)(&rb[(j * 64 + lane) * 4]) = v;
    }
    #pragma unroll
    for (int j = 16; j < 32; ++j) { // publish chunks 16..31
      f4v v;
      #pragma unroll
      for (int e = 0; e < 4; ++e) v[e] = ACC_EL(j, e);
      *(f4v*)(&rb[(j * 64 + lane) * 4]) = v;
    }
  }
  __syncthreads();

  // final: wave kb sums its quarter (chunks 8*kb .. 8*kb+8) and stores
  {
    const int lh4 = lh << 2;
    const int nfb = (kb & 1) * 2;   // quarter spans nf in {nfb, nfb+1}
    float bv[2];
    bv[0] = bias[n0 + (nfb + 0) * 32 + lc];
    bv[1] = bias[n0 + (nfb + 1) * 32 + lc];

    #pragma unroll
    for (int jj = 0; jj < 8; ++jj) {
      f4v v;
      if (kb == 0) {                // j = jj: regs(sum02) + band1(sum13)
        const int j = jj;
        const f4v w = *(const f4v*)(&red[8192 + (j * 64 + lane) * 4]);
        #pragma unroll
        for (int e = 0; e < 4; ++e) v[e] = ACC_EL(j, e) + w[e];
      } else if (kb == 1) {         // j = 8+jj: regs(sum13) + band0(sum02)
        const int j = 8 + jj;
        const f4v w = *(const f4v*)(&red[(j * 64 + lane) * 4]);
        #pragma unroll
        for (int e = 0; e < 4; ++e) v[e] = ACC_EL(j, e) + w[e];
      } else {                      // j = 8*kb+jj: band0 + band1
        const int j = kb * 8 + jj;
        const f4v w0 = *(const f4v*)(&red[(j * 64 + lane) * 4]);
        const f4v w1 = *(const f4v*)(&red[8192 + (j * 64 + lane) * 4]);
        #pragma unroll
        for (int e = 0; e < 4; ++e) v[e] = w0[e] + w1[e];
      }
      const int j = kb * 8 + jj;
      const int mf = j >> 4;
      const int nf = (j >> 2) & 3;
      const int q  = j & 3;
      const int col = n0 + nf * 32 + lc;
      const int row = m0 + mf * 32 + q * 8 + lh4;
      const float b = bv[nf - nfb];
      #pragma unroll
      for (int e = 0; e < 4; ++e)
        C[(row + e) * ND + col] = v[e] + b;
    }
  }
  #undef ACC_EL
}

extern "C" void kernel_launch(void* const* d_in, const int* in_sizes, int n_in,
                              void* d_out, int out_size, void* d_ws, size_t ws_size,
                              hipStream_t stream) {
  (void)hipFuncSetAttribute((const void*)circ_mm,
                            hipFuncAttributeMaxDynamicSharedMemorySize, 65536);
  const float* X    = (const float*)d_in[0];
  const float* W    = (const float*)d_in[1];
  const float* bias = (const float*)d_in[2];
  unsigned short* wlg = (unsigned short*)d_ws;            // 64 KB table
  unsigned short* Xpk = (unsigned short*)d_ws + 32768;    // 8 MB octet-major X

  prep<<<dim3(1088), dim3(256), 0, stream>>>(X, W, Xpk, (unsigned int*)wlg);
  circ_mm<<<dim3(512), dim3(256), 65536, stream>>>(Xpk, wlg, bias, (float*)d_out);
}

// Round 12
// 39.065 us; speedup vs baseline: 1.6683x; 1.0065x over previous
//
#include <hip/hip_runtime.h>

typedef short s8v __attribute__((ext_vector_type(8)));
typedef float f4v __attribute__((ext_vector_type(4)));
typedef float f16v __attribute__((ext_vector_type(16)));

#define ND 4096
#define NMASK 4095

__device__ __forceinline__ unsigned short f2bf(float f) {
  __bf16 h = (__bf16)f;
  return __builtin_bit_cast(unsigned short, h);
}

__device__ __forceinline__ void gload_lds16(const void* g, void* l) {
  __builtin_amdgcn_global_load_lds(
      (const __attribute__((address_space(1))) unsigned int*)g,
      (__attribute__((address_space(3))) unsigned int*)l, 16, 0, 0);
}

// Fused prep:
//  blocks [0,1024):  X f32 -> bf16 in OCTET-MAJOR layout
//                    Xpk[(oct*1024 + row)*8 + j] = bf16(X[row][oct*8+j])
//  blocks [1024,1088): 8-fold sliding-window W table:
//                    wlg[8s+t] = bf16(W[(s+t)&4095])
__global__ __launch_bounds__(256)
void prep(const float* __restrict__ X, const float* __restrict__ W,
          unsigned short* __restrict__ Xpk, unsigned int* __restrict__ wlg) {
  const int b = blockIdx.x;
  const int tid = threadIdx.x;
  if (b < 1024) {
    const int r0 = (b & 15) << 6;        // 64-row band
    const int k0 = (b >> 4) << 6;        // 64-k band
    const int r = tid >> 2;
    const int kseg = tid & 3;            // 16 k each
    const int row = r0 + r;
    const int k = k0 + (kseg << 4);
    const float* src = X + row * ND + k;
    const f4v g0 = *(const f4v*)(src + 0);
    const f4v g1 = *(const f4v*)(src + 4);
    const f4v g2 = *(const f4v*)(src + 8);
    const f4v g3 = *(const f4v*)(src + 12);
    s8v u0, u1;
    #pragma unroll
    for (int j = 0; j < 4; ++j) {
      u0[j] = (short)f2bf(g0[j]); u0[4 + j] = (short)f2bf(g1[j]);
      u1[j] = (short)f2bf(g2[j]); u1[4 + j] = (short)f2bf(g3[j]);
    }
    const int o0 = k >> 3;
    *(s8v*)(Xpk + ((o0 * 1024 + row) << 3))       = u0;
    *(s8v*)(Xpk + (((o0 + 1) * 1024 + row) << 3)) = u1;
  } else {
    const int m = (b - 1024) * 256 + tid;   // uint slot 0..16383
    const int e0 = m << 1, e1 = e0 + 1;
    const int i0 = ((e0 >> 3) + (e0 & 7)) & NMASK;
    const int i1 = ((e1 >> 3) + (e1 & 7)) & NMASK;
    wlg[m] = (unsigned int)f2bf(W[i0]) | ((unsigned int)f2bf(W[i1]) << 16);
  }
}

// BM=64, BN=256, BK=64. 512 threads = 8 waves = 2 wn-bands x 4 kb.
// GRID = 256 = exactly 1 block/CU, SINGLE PASS (occupancy counters showed
// only one block ever resides per CU; the old grid=512 ran 2 sequential
// passes at 1 wave/SIMD). Wave (wn,kb): 64 rows x 128 cols (2x4 frags of
// 32x32x16) over K-quarter kb. SIMD s hosts wn0/wn1 of kb=s -> 2 waves/SIMD
// interleave; one wave's MFMA cluster hides the other's load/issue overhead.
// MAIN LOOP: fully unrolled, branch-free; A depth-2 (3-buf), B depth-1
// (2-buf); no barriers, no LDS writes.
// EPILOGUE: per wn-group 4-way positional reduction (R11 scheme) in
// disjoint 64 KB LDS halves; every wave stores a quarter.
__global__ __launch_bounds__(512, 2)
void circ_mm(const unsigned short* __restrict__ Xpk,
             const unsigned short* __restrict__ wlg,
             const float* __restrict__ bias, float* __restrict__ C) {
  extern __shared__ unsigned short smem[];
  unsigned char* __restrict__ sb = (unsigned char*)smem;   // wl: first 64 KB

  const int tid = threadIdx.x;
  const int bid = blockIdx.x;
  // XCD-aware mapping: XCD x serves m-tiles {x, x+8}; 16 n-tiles share the
  // Xpk panel in that XCD's L2.
  const int x = bid & 7;
  const int i = bid >> 3;               // 0..31
  const int m0 = (x + ((i >> 4) << 3)) << 6;   // 16 m-tiles of 64 rows
  const int n0 = (i & 15) << 8;                // 16 n-tiles of 256 cols

  const int lane = tid & 63;
  const int wv = tid >> 6;          // 0..7
  const int kb = wv & 3;            // K-quarter (k16 of each 64-k tile)
  const int wn = wv >> 2;           // 128-col band

  // ---- async copy wl -> LDS (64 KB = 8 iters x 8 waves x 1 KB) ----
  #pragma unroll
  for (int it = 0; it < 8; ++it) {
    const int b = it * 8192 + (wv << 10);              // wave-uniform base
    gload_lds16((const unsigned char*)wlg + b + lane * 16, sb + b);
  }

  // ---- fragment geometry (mfma_f32_32x32x16_bf16) ----
  const int lc = lane & 31;
  const int lh = lane >> 5;
  const int lh8 = lh << 3;

  // A source: lane reads (row = m0 + mf*32 + lc, oct = t*8 + kb*2 + lh).
  const unsigned short* gXa =
      Xpk + ((((kb << 1) + lh) << 10) + m0 + lc) * 8;

  // B window indices (one per n-frag), advanced incrementally +64/tile.
  int s0 = ((kb << 4) + lh8 - (n0 + wn * 128 + 0 * 32 + lc)) & NMASK;
  int s1 = ((kb << 4) + lh8 - (n0 + wn * 128 + 1 * 32 + lc)) & NMASK;
  int s2 = ((kb << 4) + lh8 - (n0 + wn * 128 + 2 * 32 + lc)) & NMASK;
  int s3 = ((kb << 4) + lh8 - (n0 + wn * 128 + 3 * 32 + lc)) & NMASK;

  f16v acc[2][4];
  #pragma unroll
  for (int mf = 0; mf < 2; ++mf)
    #pragma unroll
    for (int nf = 0; nf < 4; ++nf)
      #pragma unroll
      for (int e = 0; e < 16; ++e) acc[mf][nf][e] = 0.f;

  s8v Ab[3][2];                     // 3-buffer A rotation (depth-2)
  s8v Bb[2][4];                     // 2-buffer B rotation (depth-1)

  // ---- prologue: issue A(0),A(1); wl resident; read B(0) ----
  Ab[0][0] = *(const s8v*)(gXa + 0);
  Ab[0][1] = *(const s8v*)(gXa + 256);
  Ab[1][0] = *(const s8v*)(gXa + 65536);
  Ab[1][1] = *(const s8v*)(gXa + 65536 + 256);
  __syncthreads();                  // wl resident (drains vmcnt incl. A loads)
  Bb[0][0] = *(const s8v*)(sb + (s0 << 4));
  Bb[0][1] = *(const s8v*)(sb + (s1 << 4));
  Bb[0][2] = *(const s8v*)(sb + (s2 << 4));
  Bb[0][3] = *(const s8v*)(sb + (s3 << 4));

  // ---- main loop: fully unrolled; A issue-distance 2, B issue-distance 1 ----
  #pragma unroll
  for (int t = 0; t < 64; ++t) {
    if (t + 2 < 64) {               // compile-time condition
      const unsigned short* gp = gXa + (t + 2) * 65536;
      Ab[(t + 2) % 3][0] = *(const s8v*)(gp + 0);
      Ab[(t + 2) % 3][1] = *(const s8v*)(gp + 256);
    }
    if (t + 1 < 64) {               // compile-time condition
      s0 = (s0 + 64) & NMASK;
      s1 = (s1 + 64) & NMASK;
      s2 = (s2 + 64) & NMASK;
      s3 = (s3 + 64) & NMASK;
      Bb[(t + 1) & 1][0] = *(const s8v*)(sb + (s0 << 4));
      Bb[(t + 1) & 1][1] = *(const s8v*)(sb + (s1 << 4));
      Bb[(t + 1) & 1][2] = *(const s8v*)(sb + (s2 << 4));
      Bb[(t + 1) & 1][3] = *(const s8v*)(sb + (s3 << 4));
    }

    const s8v a0 = Ab[t % 3][0];
    const s8v a1 = Ab[t % 3][1];
    __builtin_amdgcn_s_setprio(1);
    acc[0][0] = __builtin_amdgcn_mfma_f32_32x32x16_bf16(a0, Bb[t & 1][0], acc[0][0], 0, 0, 0);
    acc[1][0] = __builtin_amdgcn_mfma_f32_32x32x16_bf16(a1, Bb[t & 1][0], acc[1][0], 0, 0, 0);
    acc[0][1] = __builtin_amdgcn_mfma_f32_32x32x16_bf16(a0, Bb[t & 1][1], acc[0][1], 0, 0, 0);
    acc[1][1] = __builtin_amdgcn_mfma_f32_32x32x16_bf16(a1, Bb[t & 1][1], acc[1][1], 0, 0, 0);
    acc[0][2] = __builtin_amdgcn_mfma_f32_32x32x16_bf16(a0, Bb[t & 1][2], acc[0][2], 0, 0, 0);
    acc[1][2] = __builtin_amdgcn_mfma_f32_32x32x16_bf16(a1, Bb[t & 1][2], acc[1][2], 0, 0, 0);
    acc[0][3] = __builtin_amdgcn_mfma_f32_32x32x16_bf16(a0, Bb[t & 1][3], acc[0][3], 0, 0, 0);
    acc[1][3] = __builtin_amdgcn_mfma_f32_32x32x16_bf16(a1, Bb[t & 1][3], acc[1][3], 0, 0, 0);
    __builtin_amdgcn_s_setprio(0);
  }

  // ---- epilogue: per wn-group 4-way positional reduction, 3 barriers ----
  // chunk j = (mf*4+nf)*4+q, j in [0,32); element access by VALUE.
  #define ACC_EL(j, e) (acc[(j) >> 4][((j) >> 2) & 3][((j) & 3) * 4 + (e)])

  __syncthreads();                  // main-loop wl reads done (overlays wl)
  float* gbase = (float*)smem + wn * 16384;   // 64 KB per wn-group
  // band0 = gbase[0..8192), band1 = gbase[8192..16384)

  // step 1: kb2/kb3 dump full acc; then kb0/kb1 accumulate + publish
  if (kb == 2 || kb == 3) {
    float* rb = gbase + (kb - 2) * 8192;
    #pragma unroll
    for (int j = 0; j < 32; ++j) {
      f4v v;
      #pragma unroll
      for (int e = 0; e < 4; ++e) v[e] = ACC_EL(j, e);
      *(f4v*)(&rb[(j * 64 + lane) * 4]) = v;
    }
  }
  __syncthreads();
  if (kb == 0) {
    float* rb = gbase;              // band0: sum02 = acc + kb2
    #pragma unroll
    for (int j = 0; j < 32; ++j) {
      const f4v v = *(const f4v*)(&rb[(j * 64 + lane) * 4]);
      #pragma unroll
      for (int e = 0; e < 4; ++e) ACC_EL(j, e) += v[e];
    }
    #pragma unroll
    for (int j = 8; j < 32; ++j) {  // publish chunks 8..31
      f4v v;
      #pragma unroll
      for (int e = 0; e < 4; ++e) v[e] = ACC_EL(j, e);
      *(f4v*)(&rb[(j * 64 + lane) * 4]) = v;
    }
  }
  if (kb == 1) {
    float* rb = gbase + 8192;       // band1: sum13 = acc + kb3
    #pragma unroll
    for (int j = 0; j < 32; ++j) {
      const f4v v = *(const f4v*)(&rb[(j * 64 + lane) * 4]);
      #pragma unroll
      for (int e = 0; e < 4; ++e) ACC_EL(j, e) += v[e];
    }
    #pragma unroll
    for (int j = 0; j < 8; ++j) {   // publish chunks 0..7
      f4v v;
      #pragma unroll
      for (int e = 0; e < 4; ++e) v[e] = ACC_EL(j, e);
      *(f4v*)(&rb[(j * 64 + lane) * 4]) = v;
    }
    #pragma unroll
    for (int j = 16; j < 32; ++j) { // publish chunks 16..31
      f4v v;
      #pragma unroll
      for (int e = 0; e < 4; ++e) v[e] = ACC_EL(j, e);
      *(f4v*)(&rb[(j * 64 + lane) * 4]) = v;
    }
  }
  __syncthreads();

  // final: wave (wn,kb) sums its quarter (chunks 8*kb .. 8*kb+8) and stores
  {
    const int lh4 = lh << 2;
    const int nfb = (kb & 1) * 2;   // quarter spans nf in {nfb, nfb+1}
    float bv[2];
    bv[0] = bias[n0 + wn * 128 + (nfb + 0) * 32 + lc];
    bv[1] = bias[n0 + wn * 128 + (nfb + 1) * 32 + lc];

    #pragma unroll
    for (int jj = 0; jj < 8; ++jj) {
      f4v v;
      if (kb == 0) {                // j = jj: regs(sum02) + band1(sum13)
        const int j = jj;
        const f4v w = *(const f4v*)(&gbase[8192 + (j * 64 + lane) * 4]);
        #pragma unroll
        for (int e = 0; e < 4; ++e) v[e] = ACC_EL(j, e) + w[e];
      } else if (kb == 1) {         // j = 8+jj: regs(sum13) + band0(sum02)
        const int j = 8 + jj;
        const f4v w = *(const f4v*)(&gbase[(j * 64 + lane) * 4]);
        #pragma unroll
        for (int e = 0; e < 4; ++e) v[e] = ACC_EL(j, e) + w[e];
      } else {                      // j = 8*kb+jj: band0 + band1
        const int j = kb * 8 + jj;
        const f4v w0 = *(const f4v*)(&gbase[(j * 64 + lane) * 4]);
        const f4v w1 = *(const f4v*)(&gbase[8192 + (j * 64 + lane) * 4]);
        #pragma unroll
        for (int e = 0; e < 4; ++e) v[e] = w0[e] + w1[e];
      }
      const int j = kb * 8 + jj;
      const int mf = j >> 4;
      const int nf = (j >> 2) & 3;
      const int q  = j & 3;
      const int col = n0 + wn * 128 + nf * 32 + lc;
      const int row = m0 + mf * 32 + q * 8 + lh4;
      const float b = bv[nf - nfb];
      #pragma unroll
      for (int e = 0; e < 4; ++e)
        C[(row + e) * ND + col] = v[e] + b;
    }
  }
  #undef ACC_EL
}

extern "C" void kernel_launch(void* const* d_in, const int* in_sizes, int n_in,
                              void* d_out, int out_size, void* d_ws, size_t ws_size,
                              hipStream_t stream) {
  (void)hipFuncSetAttribute((const void*)circ_mm,
                            hipFuncAttributeMaxDynamicSharedMemorySize, 131072);
  const float* X    = (const float*)d_in[0];
  const float* W    = (const float*)d_in[1];
  const float* bias = (const float*)d_in[2];
  unsigned short* wlg = (unsigned short*)d_ws;            // 64 KB table
  unsigned short* Xpk = (unsigned short*)d_ws + 32768;    // 8 MB octet-major X

  prep<<<dim3(1088), dim3(256), 0, stream>>>(X, W, Xpk, (unsigned int*)wlg);
  circ_mm<<<dim3(256), dim3(512), 131072, stream>>>(Xpk, wlg, bias, (float*)d_out);
}